// Round 10
// baseline (218.420 us; speedup 1.0000x reference)
//
#include <hip/hip_runtime.h>
#include <hip/hip_bf16.h>
#include <math.h>

#define B_SZ   2
#define S_LEN  2048
#define C_DIM  1280
#define H_NUM  20
#define D_HEAD 64
#define M_TOT  (B_SZ * S_LEN)          // 4096

typedef __bf16 bf16;
typedef __bf16 bf16x8 __attribute__((ext_vector_type(8)));
typedef __bf16 bf16x4 __attribute__((ext_vector_type(4)));
typedef float  f32x4  __attribute__((ext_vector_type(4)));

__device__ inline f32x4 zero4() { f32x4 z; z[0]=z[1]=z[2]=z[3]=0.f; return z; }

// async global->LDS, 16B per lane. LDS dest must be wave-uniform base + lane*16.
__device__ __forceinline__ void async_copy16(void* lds, const void* g) {
    __builtin_amdgcn_global_load_lds(
        (const __attribute__((address_space(1))) unsigned int*)g,
        (__attribute__((address_space(3))) unsigned int*)lds,
        16, 0, 0);
}

// ---------------- hs fp32 -> bf16 ----------------
__global__ __launch_bounds__(256) void k_convert_hs(const float* __restrict__ in,
                                                    bf16* __restrict__ out) {
    int i = (blockIdx.x * 256 + threadIdx.x) * 4;
    float4 v = *(const float4*)(in + i);
    bf16x4 o; o[0]=(bf16)v.x; o[1]=(bf16)v.y; o[2]=(bf16)v.z; o[3]=(bf16)v.w;
    *(bf16x4*)(out + i) = o;
}

// ------------- W fp32 [K][N] -> bf16 WT [N][K] -------------
__global__ __launch_bounds__(256) void k_transpose_w(
    const float* __restrict__ w0, const float* __restrict__ w1,
    const float* __restrict__ w2, const float* __restrict__ w3,
    bf16* __restrict__ o0, bf16* __restrict__ o1,
    bf16* __restrict__ o2, bf16* __restrict__ o3) {
    __shared__ float t[32][33];
    const float* w = blockIdx.z==0 ? w0 : blockIdx.z==1 ? w1 : blockIdx.z==2 ? w2 : w3;
    bf16*       o  = blockIdx.z==0 ? o0 : blockIdx.z==1 ? o1 : blockIdx.z==2 ? o2 : o3;
    int k0 = blockIdx.y*32, n0 = blockIdx.x*32;
    int tx = threadIdx.x & 31, ty = threadIdx.x >> 5;   // 32 x 8
    #pragma unroll
    for (int i = 0; i < 32; i += 8)
        t[ty+i][tx] = w[(size_t)(k0+ty+i)*C_DIM + n0 + tx];
    __syncthreads();
    #pragma unroll
    for (int i = 0; i < 32; i += 8)
        o[(size_t)(n0+ty+i)*C_DIM + k0 + tx] = (bf16)t[tx][ty+i];
}

// ------------- QKV GEMM: [4096x1280] @ [1280x1280] -> Q/K [B,H,S,D], V^T [B,H,D,S] -------------
#define BM 128
#define BN 128
#define BK 32
__global__ __launch_bounds__(256) void k_gemm_qkv(
    const bf16* __restrict__ A,                      // hs_bf [4096][1280]
    const bf16* __restrict__ WqT, const bf16* __restrict__ WkT, const bf16* __restrict__ WvT,
    bf16* __restrict__ Qo, bf16* __restrict__ Ko, bf16* __restrict__ VTo) {
    __shared__ bf16 Al[BM][BK];
    __shared__ bf16 Bl[BN][BK];
    const int z = blockIdx.z;
    const bf16* BT = z==0 ? WqT : z==1 ? WkT : WvT;
    // Q scale folds 1/sqrt(D) AND log2(e) so attn can use raw exp2
    const float scale = (z==0) ? 0.18033688011112042f : 1.0f;
    const int m0 = blockIdx.y * BM, n0 = blockIdx.x * BN;
    const int tid = threadIdx.x, lane = tid & 63, wid = tid >> 6;
    const int wm = wid >> 1, wn = wid & 1;
    const int g = lane >> 4, lr = lane & 15;
    f32x4 acc[4][4];
    #pragma unroll
    for (int i=0;i<4;i++)
        #pragma unroll
        for (int j=0;j<4;j++)
            acc[i][j] = zero4();
    const int srow = tid >> 2, scol = (tid & 3) * 8;
    for (int k0 = 0; k0 < C_DIM; k0 += BK) {
        async_copy16(&Al[srow][scol],    &A [(size_t)(m0+srow)*C_DIM    + k0 + scol]);
        async_copy16(&Al[srow+64][scol], &A [(size_t)(m0+srow+64)*C_DIM + k0 + scol]);
        async_copy16(&Bl[srow][scol],    &BT[(size_t)(n0+srow)*C_DIM    + k0 + scol]);
        async_copy16(&Bl[srow+64][scol], &BT[(size_t)(n0+srow+64)*C_DIM + k0 + scol]);
        __syncthreads();
        bf16x8 af[4], bfr[4];
        #pragma unroll
        for (int mf=0;mf<4;mf++) af[mf]  = *(const bf16x8*)&Al[wm*64+mf*16+lr][g*8];
        #pragma unroll
        for (int nf=0;nf<4;nf++) bfr[nf] = *(const bf16x8*)&Bl[wn*64+nf*16+lr][g*8];
        #pragma unroll
        for (int mf=0;mf<4;mf++)
            #pragma unroll
            for (int nf=0;nf<4;nf++)
                acc[mf][nf] = __builtin_amdgcn_mfma_f32_16x16x32_bf16(af[mf], bfr[nf], acc[mf][nf], 0,0,0);
        __syncthreads();
    }
    if (z == 2) {
        // V: write directly transposed [B,H,D,S]; r-consecutive = s-consecutive
        #pragma unroll
        for (int mf=0;mf<4;mf++) {
            #pragma unroll
            for (int nf=0;nf<4;nf++) {
                int n = n0 + wn*64 + nf*16 + lr;
                int h = n >> 6, d = n & 63;
                int m = m0 + wm*64 + mf*16 + g*4;
                int b = m >> 11, s = m & (S_LEN-1);
                bf16x4 ov;
                #pragma unroll
                for (int r=0;r<4;r++) ov[r] = (bf16)acc[mf][nf][r];
                *(bf16x4*)&VTo[((size_t)(b*H_NUM + h)*D_HEAD + d)*S_LEN + s] = ov;
            }
        }
    } else {
        bf16* Out = (z==0) ? Qo : Ko;
        #pragma unroll
        for (int mf=0;mf<4;mf++) {
            #pragma unroll
            for (int nf=0;nf<4;nf++) {
                int n = n0 + wn*64 + nf*16 + lr;
                int h = n >> 6, d = n & 63;
                #pragma unroll
                for (int r=0;r<4;r++) {
                    int m = m0 + wm*64 + mf*16 + g*4 + r;
                    int b = m >> 11, s = m & (S_LEN-1);
                    Out[(size_t)((b*H_NUM + h)*S_LEN + s)*D_HEAD + d] = (bf16)(acc[mf][nf][r] * scale);
                }
            }
        }
    }
}

// ------------- output GEMM with bias+residual epilogue, fp32 out -------------
__global__ __launch_bounds__(256) void k_gemm_out(
    const bf16* __restrict__ A,                     // Oattn [4096][1280]
    const bf16* __restrict__ WoT,
    const float* __restrict__ bo,
    const float* __restrict__ res,                  // hidden_states fp32
    float* __restrict__ out) {
    __shared__ bf16 Al[BM][BK];
    __shared__ bf16 Bl[BN][BK];
    const int m0 = blockIdx.y * BM, n0 = blockIdx.x * BN;
    const int tid = threadIdx.x, lane = tid & 63, wid = tid >> 6;
    const int wm = wid >> 1, wn = wid & 1;
    const int g = lane >> 4, lr = lane & 15;
    f32x4 acc[4][4];
    #pragma unroll
    for (int i=0;i<4;i++)
        #pragma unroll
        for (int j=0;j<4;j++)
            acc[i][j] = zero4();
    const int srow = tid >> 2, scol = (tid & 3) * 8;
    for (int k0 = 0; k0 < C_DIM; k0 += BK) {
        async_copy16(&Al[srow][scol],    &A  [(size_t)(m0+srow)*C_DIM    + k0 + scol]);
        async_copy16(&Al[srow+64][scol], &A  [(size_t)(m0+srow+64)*C_DIM + k0 + scol]);
        async_copy16(&Bl[srow][scol],    &WoT[(size_t)(n0+srow)*C_DIM    + k0 + scol]);
        async_copy16(&Bl[srow+64][scol], &WoT[(size_t)(n0+srow+64)*C_DIM + k0 + scol]);
        __syncthreads();
        bf16x8 af[4], bfr[4];
        #pragma unroll
        for (int mf=0;mf<4;mf++) af[mf]  = *(const bf16x8*)&Al[wm*64+mf*16+lr][g*8];
        #pragma unroll
        for (int nf=0;nf<4;nf++) bfr[nf] = *(const bf16x8*)&Bl[wn*64+nf*16+lr][g*8];
        #pragma unroll
        for (int mf=0;mf<4;mf++)
            #pragma unroll
            for (int nf=0;nf<4;nf++)
                acc[mf][nf] = __builtin_amdgcn_mfma_f32_16x16x32_bf16(af[mf], bfr[nf], acc[mf][nf], 0,0,0);
        __syncthreads();
    }
    #pragma unroll
    for (int mf=0;mf<4;mf++) {
        #pragma unroll
        for (int nf=0;nf<4;nf++) {
            int n = n0 + wn*64 + nf*16 + lr;
            float bias = bo[n];
            #pragma unroll
            for (int r=0;r<4;r++) {
                int m = m0 + wm*64 + mf*16 + g*4 + r;
                size_t idx = (size_t)m*C_DIM + n;
                out[idx] = acc[mf][nf][r] + bias + res[idx];
            }
        }
    }
}

// ------------- flash attention + loss partials -------------
// Swapped-operand flash attn (R8 structure). Q pre-scaled by log2e/8 -> raw
// exp2. l computed by MFMA with A=ones (2 extra MFMA/tile replace 16 VALU
// adds; result fully k-reduced, no final shuffles). s2 stays lane-local fma.
#define KVB 64
__global__ __launch_bounds__(256) void k_attn(
    const bf16* __restrict__ Q,    // [B,H,S,D], pre-scaled by log2e/8
    const bf16* __restrict__ Kg,   // [B,H,S,D]
    const bf16* __restrict__ VT,   // [B,H,D,S]
    bf16* __restrict__ O,          // [B,S,H,D]
    float* __restrict__ lossPart) {
    __shared__ bf16 Kl[2][KVB][64];
    __shared__ bf16 Vl[2][D_HEAD][64];   // total LDS = 32768 B exactly

    const int qb = blockIdx.x;         // 0..31 (64 q-rows per block)
    const int bh = blockIdx.y;         // 0..39
    const int b = bh / H_NUM, hh = bh % H_NUM;
    const int tid = threadIdx.x, lane = tid & 63, wid = tid >> 6;
    const int g = lane >> 4, lr = lane & 15;

    const bf16* Kbase = Kg + (size_t)bh * S_LEN * D_HEAD;
    const bf16* Vbase = VT + (size_t)bh * D_HEAD * S_LEN;

    // per-lane q row
    const int qrow = qb*64 + wid*16 + lr;
    const bf16* qp = Q + ((size_t)bh*S_LEN + qrow)*D_HEAD;
    const bf16x8 aq0 = *(const bf16x8*)(qp + g*8);        // Q^T B-frag, d-half 0
    const bf16x8 aq1 = *(const bf16x8*)(qp + 32 + g*8);   // d-half 1

    // ones A-fragment for the l-MFMA
    bf16x8 ones;
    #pragma unroll
    for (int i=0;i<8;i++) ones[i] = (bf16)1.0f;

    // K LDS read-row components (phys kv -> LDS row sigma: swap bits 2,3)
    const int lb7 = (lr & 3) | (((lr >> 2) & 1) << 2);    // LDS row bits 0..2
    const int lhi = ((lr >> 2) & 2) << 3;                 // LDS row bit 4

    f32x4 o_acc[4];
    #pragma unroll
    for (int i=0;i<4;i++) o_acc[i] = zero4();
    f32x4 l_acc = zero4();
    float s2acc = 0.f;

#define STAGE(buf, kv0)                                                          \
    {                                                                            \
        _Pragma("unroll")                                                        \
        for (int pp=0; pp<2; ++pp) {                                             \
            int p = pp*256 + tid;                                                \
            int lrow = p >> 3, gp = p & 7;                                       \
            int tl = (lrow & 51) | ((lrow & 4) << 1) | ((lrow & 8) >> 1);        \
            async_copy16((char*)&Kl[buf][0][0] + p*16,                           \
                         Kbase + (size_t)((kv0) + tl)*D_HEAD                     \
                               + ((gp ^ (lrow & 7)) << 3));                      \
        }                                                                        \
        _Pragma("unroll")                                                        \
        for (int pp=0; pp<2; ++pp) {                                             \
            int p = pp*256 + tid;                                                \
            int drow = p >> 3, gp = p & 7;                                       \
            async_copy16((char*)&Vl[buf][0][0] + p*16,                           \
                         Vbase + (size_t)drow*S_LEN + (kv0)                      \
                               + ((gp ^ (drow & 7)) << 3));                      \
        }                                                                        \
    }

    STAGE(0, 0);
    __syncthreads();

    for (int t = 0; t < S_LEN/KVB; ++t) {
        const int cur = t & 1;
        if (t + 1 < S_LEN/KVB) STAGE(cur^1, (t+1)*KVB);
        const bf16* KB = &Kl[cur][0][0];
        const bf16* VB = &Vl[cur][0][0];

        // QK^T (swapped): acc_p[pair][u][r] = S^T[kv = pair*32+g*8+u*4+r][q=qrow]
        f32x4 accp[2][2];
        #pragma unroll
        for (int pair=0; pair<2; ++pair)
            #pragma unroll
            for (int u=0; u<2; ++u) {
                const bf16* kr = KB + (pair*32 + (u<<3) + lhi + lb7)*64;
                bf16x8 k0 = *(const bf16x8*)(kr + ((g       ^ lb7) << 3));
                bf16x8 k1 = *(const bf16x8*)(kr + (((4 + g) ^ lb7) << 3));
                f32x4 c = zero4();
                c = __builtin_amdgcn_mfma_f32_16x16x32_bf16(k0, aq0, c, 0,0,0);
                c = __builtin_amdgcn_mfma_f32_16x16x32_bf16(k1, aq1, c, 0,0,0);
                accp[pair][u] = c;
            }
        // unnormalized p = exp2(s'): lane-local; pack PV B-fragment in registers
        bf16x8 pb[2];
        #pragma unroll
        for (int pair=0; pair<2; ++pair)
            #pragma unroll
            for (int u=0; u<2; ++u)
                #pragma unroll
                for (int r=0; r<4; ++r) {
                    float e = exp2f(accp[pair][u][r]);
                    s2acc += e*e;
                    pb[pair][u*4+r] = (bf16)e;
                }
        // l via MFMA (A=ones): fully k-reduced Sum(p) per q column
        l_acc = __builtin_amdgcn_mfma_f32_16x16x32_bf16(ones, pb[0], l_acc, 0,0,0);
        l_acc = __builtin_amdgcn_mfma_f32_16x16x32_bf16(ones, pb[1], l_acc, 0,0,0);
        // PV: O^T += V^T . P^T
        #pragma unroll
        for (int ds_=0; ds_<4; ++ds_) {
            const bf16* vr = VB + (ds_*16 + lr)*64;
            #pragma unroll
            for (int pair=0; pair<2; ++pair) {
                bf16x8 v = *(const bf16x8*)(vr + (((pair*4 + g) ^ (lr & 7)) << 3));
                o_acc[ds_] = __builtin_amdgcn_mfma_f32_16x16x32_bf16(v, pb[pair], o_acc[ds_], 0,0,0);
            }
        }
        __syncthreads();   // stage t+1 complete; all waves done with cur
    }

    // l is already complete per q column (MFMA sums all k); s2 needs g-reduce
    const float lfull = l_acc[0];
    float s2full = s2acc;
    s2full += __shfl_xor(s2full, 16); s2full += __shfl_xor(s2full, 32);

    // O write: lane owns q=qrow, holds O^T[d = ds_*16+g*4+r]
    const float inv = 1.0f / lfull;
    bf16* orow = O + ((size_t)(b*S_LEN + qrow)*H_NUM + hh)*D_HEAD;
    #pragma unroll
    for (int ds_=0; ds_<4; ++ds_) {
        bf16x4 ov;
        #pragma unroll
        for (int r=0; r<4; ++r) ov[r] = (bf16)(o_acc[ds_][r] * inv);
        *(bf16x4*)(orow + ds_*16 + g*4) = ov;
    }
    // loss partial: per-wave, straight to global.
    // sum over q of s2/l^2; each q replicated 4x across g -> /4.
    float v = s2full / (lfull*lfull);
    #pragma unroll
    for (int msk=1; msk<64; msk<<=1) v += __shfl_xor(v, msk);
    v *= 0.25f;
    if (lane == 0) lossPart[(bh*32 + qb)*4 + wid] = v;
}

// ------------- deterministic loss reduce -------------
__global__ __launch_bounds__(256) void k_loss(const float* __restrict__ part,
                                              float* __restrict__ out, int n) {
    __shared__ float w[4];
    float s = 0.f;
    for (int i = threadIdx.x; i < n; i += 256) s += part[i];
    #pragma unroll
    for (int msk=1; msk<64; msk<<=1) s += __shfl_xor(s, msk);
    int lane = threadIdx.x & 63, wid = threadIdx.x >> 6;
    if (lane==0) w[wid] = s;
    __syncthreads();
    if (threadIdx.x==0) out[(size_t)M_TOT*C_DIM] = sqrtf(w[0]+w[1]+w[2]+w[3]);
}

extern "C" void kernel_launch(void* const* d_in, const int* in_sizes, int n_in,
                              void* d_out, int out_size, void* d_ws, size_t ws_size,
                              hipStream_t stream) {
    (void)in_sizes; (void)n_in; (void)out_size; (void)ws_size;
    const float* hs = (const float*)d_in[0];
    const float* Wq = (const float*)d_in[1];
    const float* Wk = (const float*)d_in[2];
    const float* Wv = (const float*)d_in[3];
    const float* Wo = (const float*)d_in[4];
    const float* bo = (const float*)d_in[5];
    float* out = (float*)d_out;

    constexpr size_t HS_E = (size_t)M_TOT * C_DIM;       // 5,242,880
    constexpr size_t W_E  = (size_t)C_DIM * C_DIM;       // 1,638,400
    char* ws = (char*)d_ws;
    size_t off = 0;
    bf16* hs_bf = (bf16*)(ws + off); off += HS_E * 2;
    bf16* WqT   = (bf16*)(ws + off); off += W_E * 2;
    bf16* WkT   = (bf16*)(ws + off); off += W_E * 2;
    bf16* WvT   = (bf16*)(ws + off); off += W_E * 2;
    bf16* WoT   = (bf16*)(ws + off); off += W_E * 2;
    bf16* Qb    = (bf16*)(ws + off); off += HS_E * 2;
    bf16* Kb    = (bf16*)(ws + off); off += HS_E * 2;
    bf16* Vtb   = (bf16*)(ws + off); off += HS_E * 2;    // V^T [B,H,D,S], written by gemm
    bf16* Ob    = (bf16*)(ws + off); off += HS_E * 2;
    float* lossPart = (float*)(ws + off); off += 5120 * 4;

    k_convert_hs<<<HS_E/(256*4), 256, 0, stream>>>(hs, hs_bf);
    k_transpose_w<<<dim3(C_DIM/32, C_DIM/32, 4), 256, 0, stream>>>(Wq, Wk, Wv, Wo, WqT, WkT, WvT, WoT);
    k_gemm_qkv<<<dim3(C_DIM/BN, M_TOT/BM, 3), 256, 0, stream>>>(hs_bf, WqT, WkT, WvT, Qb, Kb, Vtb);
    k_attn<<<dim3(S_LEN/64, B_SZ*H_NUM), 256, 0, stream>>>(Qb, Kb, Vtb, Ob, lossPart);
    k_gemm_out<<<dim3(C_DIM/BN, M_TOT/BM), 256, 0, stream>>>(Ob, WoT, bo, hs, out);
    k_loss<<<1, 256, 0, stream>>>(lossPart, out, 5120);
}

// Round 11
// 207.394 us; speedup vs baseline: 1.0532x; 1.0532x over previous
//
#include <hip/hip_runtime.h>
#include <hip/hip_bf16.h>
#include <math.h>

#define B_SZ   2
#define S_LEN  2048
#define C_DIM  1280
#define H_NUM  20
#define D_HEAD 64
#define M_TOT  (B_SZ * S_LEN)          // 4096

typedef __bf16 bf16;
typedef __bf16 bf16x8 __attribute__((ext_vector_type(8)));
typedef __bf16 bf16x4 __attribute__((ext_vector_type(4)));
typedef float  f32x4  __attribute__((ext_vector_type(4)));

__device__ inline f32x4 zero4() { f32x4 z; z[0]=z[1]=z[2]=z[3]=0.f; return z; }

// async global->LDS, 16B per lane. LDS dest must be wave-uniform base + lane*16.
__device__ __forceinline__ void async_copy16(void* lds, const void* g) {
    __builtin_amdgcn_global_load_lds(
        (const __attribute__((address_space(1))) unsigned int*)g,
        (__attribute__((address_space(3))) unsigned int*)lds,
        16, 0, 0);
}

// ---------------- hs fp32 -> bf16 ----------------
__global__ __launch_bounds__(256) void k_convert_hs(const float* __restrict__ in,
                                                    bf16* __restrict__ out) {
    int i = (blockIdx.x * 256 + threadIdx.x) * 4;
    float4 v = *(const float4*)(in + i);
    bf16x4 o; o[0]=(bf16)v.x; o[1]=(bf16)v.y; o[2]=(bf16)v.z; o[3]=(bf16)v.w;
    *(bf16x4*)(out + i) = o;
}

// ------------- W fp32 [K][N] -> bf16 WT [N][K] -------------
__global__ __launch_bounds__(256) void k_transpose_w(
    const float* __restrict__ w0, const float* __restrict__ w1,
    const float* __restrict__ w2, const float* __restrict__ w3,
    bf16* __restrict__ o0, bf16* __restrict__ o1,
    bf16* __restrict__ o2, bf16* __restrict__ o3) {
    __shared__ float t[32][33];
    const float* w = blockIdx.z==0 ? w0 : blockIdx.z==1 ? w1 : blockIdx.z==2 ? w2 : w3;
    bf16*       o  = blockIdx.z==0 ? o0 : blockIdx.z==1 ? o1 : blockIdx.z==2 ? o2 : o3;
    int k0 = blockIdx.y*32, n0 = blockIdx.x*32;
    int tx = threadIdx.x & 31, ty = threadIdx.x >> 5;   // 32 x 8
    #pragma unroll
    for (int i = 0; i < 32; i += 8)
        t[ty+i][tx] = w[(size_t)(k0+ty+i)*C_DIM + n0 + tx];
    __syncthreads();
    #pragma unroll
    for (int i = 0; i < 32; i += 8)
        o[(size_t)(n0+ty+i)*C_DIM + k0 + tx] = (bf16)t[tx][ty+i];
}

// ------------- QKV GEMM: [4096x1280] @ [1280x1280] -> Q/K [B,H,S,D], V^T [B,H,D,S] -------------
#define BM 128
#define BN 128
#define BK 32
__global__ __launch_bounds__(256) void k_gemm_qkv(
    const bf16* __restrict__ A,                      // hs_bf [4096][1280]
    const bf16* __restrict__ WqT, const bf16* __restrict__ WkT, const bf16* __restrict__ WvT,
    bf16* __restrict__ Qo, bf16* __restrict__ Ko, bf16* __restrict__ VTo) {
    __shared__ bf16 Al[BM][BK];
    __shared__ bf16 Bl[BN][BK];
    const int z = blockIdx.z;
    const bf16* BT = z==0 ? WqT : z==1 ? WkT : WvT;
    // Q scale folds 1/sqrt(D) AND log2(e) so attn can use raw v_exp (exp2)
    const float scale = (z==0) ? 0.18033688011112042f : 1.0f;
    const int m0 = blockIdx.y * BM, n0 = blockIdx.x * BN;
    const int tid = threadIdx.x, lane = tid & 63, wid = tid >> 6;
    const int wm = wid >> 1, wn = wid & 1;
    const int g = lane >> 4, lr = lane & 15;
    f32x4 acc[4][4];
    #pragma unroll
    for (int i=0;i<4;i++)
        #pragma unroll
        for (int j=0;j<4;j++)
            acc[i][j] = zero4();
    const int srow = tid >> 2, scol = (tid & 3) * 8;
    for (int k0 = 0; k0 < C_DIM; k0 += BK) {
        async_copy16(&Al[srow][scol],    &A [(size_t)(m0+srow)*C_DIM    + k0 + scol]);
        async_copy16(&Al[srow+64][scol], &A [(size_t)(m0+srow+64)*C_DIM + k0 + scol]);
        async_copy16(&Bl[srow][scol],    &BT[(size_t)(n0+srow)*C_DIM    + k0 + scol]);
        async_copy16(&Bl[srow+64][scol], &BT[(size_t)(n0+srow+64)*C_DIM + k0 + scol]);
        __syncthreads();
        bf16x8 af[4], bfr[4];
        #pragma unroll
        for (int mf=0;mf<4;mf++) af[mf]  = *(const bf16x8*)&Al[wm*64+mf*16+lr][g*8];
        #pragma unroll
        for (int nf=0;nf<4;nf++) bfr[nf] = *(const bf16x8*)&Bl[wn*64+nf*16+lr][g*8];
        #pragma unroll
        for (int mf=0;mf<4;mf++)
            #pragma unroll
            for (int nf=0;nf<4;nf++)
                acc[mf][nf] = __builtin_amdgcn_mfma_f32_16x16x32_bf16(af[mf], bfr[nf], acc[mf][nf], 0,0,0);
        __syncthreads();
    }
    if (z == 2) {
        // V: write directly transposed [B,H,D,S]; r-consecutive = s-consecutive
        #pragma unroll
        for (int mf=0;mf<4;mf++) {
            #pragma unroll
            for (int nf=0;nf<4;nf++) {
                int n = n0 + wn*64 + nf*16 + lr;
                int h = n >> 6, d = n & 63;
                int m = m0 + wm*64 + mf*16 + g*4;
                int b = m >> 11, s = m & (S_LEN-1);
                bf16x4 ov;
                #pragma unroll
                for (int r=0;r<4;r++) ov[r] = (bf16)acc[mf][nf][r];
                *(bf16x4*)&VTo[((size_t)(b*H_NUM + h)*D_HEAD + d)*S_LEN + s] = ov;
            }
        }
    } else {
        bf16* Out = (z==0) ? Qo : Ko;
        #pragma unroll
        for (int mf=0;mf<4;mf++) {
            #pragma unroll
            for (int nf=0;nf<4;nf++) {
                int n = n0 + wn*64 + nf*16 + lr;
                int h = n >> 6, d = n & 63;
                #pragma unroll
                for (int r=0;r<4;r++) {
                    int m = m0 + wm*64 + mf*16 + g*4 + r;
                    int b = m >> 11, s = m & (S_LEN-1);
                    Out[(size_t)((b*H_NUM + h)*S_LEN + s)*D_HEAD + d] = (bf16)(acc[mf][nf][r] * scale);
                }
            }
        }
    }
}

// ------------- output GEMM with bias+residual epilogue, fp32 out -------------
__global__ __launch_bounds__(256) void k_gemm_out(
    const bf16* __restrict__ A,                     // Oattn [4096][1280]
    const bf16* __restrict__ WoT,
    const float* __restrict__ bo,
    const float* __restrict__ res,                  // hidden_states fp32
    float* __restrict__ out) {
    __shared__ bf16 Al[BM][BK];
    __shared__ bf16 Bl[BN][BK];
    const int m0 = blockIdx.y * BM, n0 = blockIdx.x * BN;
    const int tid = threadIdx.x, lane = tid & 63, wid = tid >> 6;
    const int wm = wid >> 1, wn = wid & 1;
    const int g = lane >> 4, lr = lane & 15;
    f32x4 acc[4][4];
    #pragma unroll
    for (int i=0;i<4;i++)
        #pragma unroll
        for (int j=0;j<4;j++)
            acc[i][j] = zero4();
    const int srow = tid >> 2, scol = (tid & 3) * 8;
    for (int k0 = 0; k0 < C_DIM; k0 += BK) {
        async_copy16(&Al[srow][scol],    &A  [(size_t)(m0+srow)*C_DIM    + k0 + scol]);
        async_copy16(&Al[srow+64][scol], &A  [(size_t)(m0+srow+64)*C_DIM + k0 + scol]);
        async_copy16(&Bl[srow][scol],    &WoT[(size_t)(n0+srow)*C_DIM    + k0 + scol]);
        async_copy16(&Bl[srow+64][scol], &WoT[(size_t)(n0+srow+64)*C_DIM + k0 + scol]);
        __syncthreads();
        bf16x8 af[4], bfr[4];
        #pragma unroll
        for (int mf=0;mf<4;mf++) af[mf]  = *(const bf16x8*)&Al[wm*64+mf*16+lr][g*8];
        #pragma unroll
        for (int nf=0;nf<4;nf++) bfr[nf] = *(const bf16x8*)&Bl[wn*64+nf*16+lr][g*8];
        #pragma unroll
        for (int mf=0;mf<4;mf++)
            #pragma unroll
            for (int nf=0;nf<4;nf++)
                acc[mf][nf] = __builtin_amdgcn_mfma_f32_16x16x32_bf16(af[mf], bfr[nf], acc[mf][nf], 0,0,0);
        __syncthreads();
    }
    #pragma unroll
    for (int mf=0;mf<4;mf++) {
        #pragma unroll
        for (int nf=0;nf<4;nf++) {
            int n = n0 + wn*64 + nf*16 + lr;
            float bias = bo[n];
            #pragma unroll
            for (int r=0;r<4;r++) {
                int m = m0 + wm*64 + mf*16 + g*4 + r;
                size_t idx = (size_t)m*C_DIM + n;
                out[idx] = acc[mf][nf][r] + bias + res[idx];
            }
        }
    }
}

// ------------- flash attention + loss partials -------------
// Swapped-operand flash attn. Q pre-scaled by log2e/8 -> raw v_exp_f32
// (__builtin_amdgcn_exp2f). l via ones-MFMA (fully k-reduced, no VALU adds).
// s2 lane-local fma. P entirely in registers; K/V dbuf LDS, 1 barrier/tile.
#define KVB 64
__global__ __launch_bounds__(256) void k_attn(
    const bf16* __restrict__ Q,    // [B,H,S,D], pre-scaled by log2e/8
    const bf16* __restrict__ Kg,   // [B,H,S,D]
    const bf16* __restrict__ VT,   // [B,H,D,S]
    bf16* __restrict__ O,          // [B,S,H,D]
    float* __restrict__ lossPart) {
    __shared__ bf16 Kl[2][KVB][64];
    __shared__ bf16 Vl[2][D_HEAD][64];   // total LDS = 32768 B exactly

    const int qb = blockIdx.x;         // 0..31 (64 q-rows per block)
    const int bh = blockIdx.y;         // 0..39
    const int b = bh / H_NUM, hh = bh % H_NUM;
    const int tid = threadIdx.x, lane = tid & 63, wid = tid >> 6;
    const int g = lane >> 4, lr = lane & 15;

    const bf16* Kbase = Kg + (size_t)bh * S_LEN * D_HEAD;
    const bf16* Vbase = VT + (size_t)bh * D_HEAD * S_LEN;

    // per-lane q row
    const int qrow = qb*64 + wid*16 + lr;
    const bf16* qp = Q + ((size_t)bh*S_LEN + qrow)*D_HEAD;
    const bf16x8 aq0 = *(const bf16x8*)(qp + g*8);        // Q^T B-frag, d-half 0
    const bf16x8 aq1 = *(const bf16x8*)(qp + 32 + g*8);   // d-half 1

    // ones A-fragment for the l-MFMA
    bf16x8 ones;
    #pragma unroll
    for (int i=0;i<8;i++) ones[i] = (bf16)1.0f;

    // K LDS read-row components (phys kv -> LDS row sigma: swap bits 2,3)
    const int lb7 = (lr & 3) | (((lr >> 2) & 1) << 2);    // LDS row bits 0..2
    const int lhi = ((lr >> 2) & 2) << 3;                 // LDS row bit 4

    f32x4 o_acc[4];
    #pragma unroll
    for (int i=0;i<4;i++) o_acc[i] = zero4();
    f32x4 l_acc = zero4();
    float s2acc = 0.f;

#define STAGE(buf, kv0)                                                          \
    {                                                                            \
        _Pragma("unroll")                                                        \
        for (int pp=0; pp<2; ++pp) {                                             \
            int p = pp*256 + tid;                                                \
            int lrow = p >> 3, gp = p & 7;                                       \
            int tl = (lrow & 51) | ((lrow & 4) << 1) | ((lrow & 8) >> 1);        \
            async_copy16((char*)&Kl[buf][0][0] + p*16,                           \
                         Kbase + (size_t)((kv0) + tl)*D_HEAD                     \
                               + ((gp ^ (lrow & 7)) << 3));                      \
        }                                                                        \
        _Pragma("unroll")                                                        \
        for (int pp=0; pp<2; ++pp) {                                             \
            int p = pp*256 + tid;                                                \
            int drow = p >> 3, gp = p & 7;                                       \
            async_copy16((char*)&Vl[buf][0][0] + p*16,                           \
                         Vbase + (size_t)drow*S_LEN + (kv0)                      \
                               + ((gp ^ (drow & 7)) << 3));                      \
        }                                                                        \
    }

    STAGE(0, 0);
    __syncthreads();

    for (int t = 0; t < S_LEN/KVB; ++t) {
        const int cur = t & 1;
        if (t + 1 < S_LEN/KVB) STAGE(cur^1, (t+1)*KVB);
        const bf16* KB = &Kl[cur][0][0];
        const bf16* VB = &Vl[cur][0][0];

        // QK^T (swapped): acc_p[pair][u][r] = S^T[kv = pair*32+g*8+u*4+r][q=qrow]
        f32x4 accp[2][2];
        #pragma unroll
        for (int pair=0; pair<2; ++pair)
            #pragma unroll
            for (int u=0; u<2; ++u) {
                const bf16* kr = KB + (pair*32 + (u<<3) + lhi + lb7)*64;
                bf16x8 k0 = *(const bf16x8*)(kr + ((g       ^ lb7) << 3));
                bf16x8 k1 = *(const bf16x8*)(kr + (((4 + g) ^ lb7) << 3));
                f32x4 c = zero4();
                c = __builtin_amdgcn_mfma_f32_16x16x32_bf16(k0, aq0, c, 0,0,0);
                c = __builtin_amdgcn_mfma_f32_16x16x32_bf16(k1, aq1, c, 0,0,0);
                accp[pair][u] = c;
            }
        // unnormalized p = 2^(s'): single v_exp_f32 each, lane-local
        bf16x8 pb[2];
        #pragma unroll
        for (int pair=0; pair<2; ++pair)
            #pragma unroll
            for (int u=0; u<2; ++u)
                #pragma unroll
                for (int r=0; r<4; ++r) {
                    float e = __builtin_amdgcn_exp2f(accp[pair][u][r]);
                    s2acc += e*e;
                    pb[pair][u*4+r] = (bf16)e;
                }
        // l via MFMA (A=ones): fully k-reduced Sum(p) per q column
        l_acc = __builtin_amdgcn_mfma_f32_16x16x32_bf16(ones, pb[0], l_acc, 0,0,0);
        l_acc = __builtin_amdgcn_mfma_f32_16x16x32_bf16(ones, pb[1], l_acc, 0,0,0);
        // PV: O^T += V^T . P^T
        #pragma unroll
        for (int ds_=0; ds_<4; ++ds_) {
            const bf16* vr = VB + (ds_*16 + lr)*64;
            #pragma unroll
            for (int pair=0; pair<2; ++pair) {
                bf16x8 v = *(const bf16x8*)(vr + (((pair*4 + g) ^ (lr & 7)) << 3));
                o_acc[ds_] = __builtin_amdgcn_mfma_f32_16x16x32_bf16(v, pb[pair], o_acc[ds_], 0,0,0);
            }
        }
        __syncthreads();   // stage t+1 complete; all waves done with cur
    }

    // l is already complete per q column (MFMA sums all k); s2 needs g-reduce
    const float lfull = l_acc[0];
    float s2full = s2acc;
    s2full += __shfl_xor(s2full, 16); s2full += __shfl_xor(s2full, 32);

    // O write: lane owns q=qrow, holds O^T[d = ds_*16+g*4+r]
    const float inv = 1.0f / lfull;
    bf16* orow = O + ((size_t)(b*S_LEN + qrow)*H_NUM + hh)*D_HEAD;
    #pragma unroll
    for (int ds_=0; ds_<4; ++ds_) {
        bf16x4 ov;
        #pragma unroll
        for (int r=0; r<4; ++r) ov[r] = (bf16)(o_acc[ds_][r] * inv);
        *(bf16x4*)(orow + ds_*16 + g*4) = ov;
    }
    // loss partial: per-wave, straight to global.
    // sum over q of s2/l^2; each q replicated 4x across g -> /4.
    float v = s2full / (lfull*lfull);
    #pragma unroll
    for (int msk=1; msk<64; msk<<=1) v += __shfl_xor(v, msk);
    v *= 0.25f;
    if (lane == 0) lossPart[(bh*32 + qb)*4 + wid] = v;
}

// ------------- deterministic loss reduce -------------
__global__ __launch_bounds__(256) void k_loss(const float* __restrict__ part,
                                              float* __restrict__ out, int n) {
    __shared__ float w[4];
    float s = 0.f;
    for (int i = threadIdx.x; i < n; i += 256) s += part[i];
    #pragma unroll
    for (int msk=1; msk<64; msk<<=1) s += __shfl_xor(s, msk);
    int lane = threadIdx.x & 63, wid = threadIdx.x >> 6;
    if (lane==0) w[wid] = s;
    __syncthreads();
    if (threadIdx.x==0) out[(size_t)M_TOT*C_DIM] = sqrtf(w[0]+w[1]+w[2]+w[3]);
}

extern "C" void kernel_launch(void* const* d_in, const int* in_sizes, int n_in,
                              void* d_out, int out_size, void* d_ws, size_t ws_size,
                              hipStream_t stream) {
    (void)in_sizes; (void)n_in; (void)out_size; (void)ws_size;
    const float* hs = (const float*)d_in[0];
    const float* Wq = (const float*)d_in[1];
    const float* Wk = (const float*)d_in[2];
    const float* Wv = (const float*)d_in[3];
    const float* Wo = (const float*)d_in[4];
    const float* bo = (const float*)d_in[5];
    float* out = (float*)d_out;

    constexpr size_t HS_E = (size_t)M_TOT * C_DIM;       // 5,242,880
    constexpr size_t W_E  = (size_t)C_DIM * C_DIM;       // 1,638,400
    char* ws = (char*)d_ws;
    size_t off = 0;
    bf16* hs_bf = (bf16*)(ws + off); off += HS_E * 2;
    bf16* WqT   = (bf16*)(ws + off); off += W_E * 2;
    bf16* WkT   = (bf16*)(ws + off); off += W_E * 2;
    bf16* WvT   = (bf16*)(ws + off); off += W_E * 2;
    bf16* WoT   = (bf16*)(ws + off); off += W_E * 2;
    bf16* Qb    = (bf16*)(ws + off); off += HS_E * 2;
    bf16* Kb    = (bf16*)(ws + off); off += HS_E * 2;
    bf16* Vtb   = (bf16*)(ws + off); off += HS_E * 2;    // V^T [B,H,D,S], written by gemm
    bf16* Ob    = (bf16*)(ws + off); off += HS_E * 2;
    float* lossPart = (float*)(ws + off); off += 5120 * 4;

    k_convert_hs<<<HS_E/(256*4), 256, 0, stream>>>(hs, hs_bf);
    k_transpose_w<<<dim3(C_DIM/32, C_DIM/32, 4), 256, 0, stream>>>(Wq, Wk, Wv, Wo, WqT, WkT, WvT, WoT);
    k_gemm_qkv<<<dim3(C_DIM/BN, M_TOT/BM, 3), 256, 0, stream>>>(hs_bf, WqT, WkT, WvT, Qb, Kb, Vtb);
    k_attn<<<dim3(S_LEN/64, B_SZ*H_NUM), 256, 0, stream>>>(Qb, Kb, Vtb, Ob, lossPart);
    k_gemm_out<<<dim3(C_DIM/BN, M_TOT/BM), 256, 0, stream>>>(Ob, WoT, bo, hs, out);
    k_loss<<<1, 256, 0, stream>>>(lossPart, out, 5120);
}

// Round 12
// 204.151 us; speedup vs baseline: 1.0699x; 1.0159x over previous
//
#include <hip/hip_runtime.h>
#include <hip/hip_bf16.h>
#include <math.h>

#define B_SZ   2
#define S_LEN  2048
#define C_DIM  1280
#define H_NUM  20
#define D_HEAD 64
#define M_TOT  (B_SZ * S_LEN)          // 4096

typedef __bf16 bf16;
typedef __bf16 bf16x8 __attribute__((ext_vector_type(8)));
typedef __bf16 bf16x4 __attribute__((ext_vector_type(4)));
typedef float  f32x4  __attribute__((ext_vector_type(4)));

__device__ inline f32x4 zero4() { f32x4 z; z[0]=z[1]=z[2]=z[3]=0.f; return z; }

// async global->LDS, 16B per lane. LDS dest must be wave-uniform base + lane*16.
__device__ __forceinline__ void async_copy16(void* lds, const void* g) {
    __builtin_amdgcn_global_load_lds(
        (const __attribute__((address_space(1))) unsigned int*)g,
        (__attribute__((address_space(3))) unsigned int*)lds,
        16, 0, 0);
}

// ---------------- hs fp32 -> bf16 ----------------
__global__ __launch_bounds__(256) void k_convert_hs(const float* __restrict__ in,
                                                    bf16* __restrict__ out) {
    int i = (blockIdx.x * 256 + threadIdx.x) * 4;
    float4 v = *(const float4*)(in + i);
    bf16x4 o; o[0]=(bf16)v.x; o[1]=(bf16)v.y; o[2]=(bf16)v.z; o[3]=(bf16)v.w;
    *(bf16x4*)(out + i) = o;
}

// ------------- W fp32 [K][N] -> bf16 WT [N][K] -------------
__global__ __launch_bounds__(256) void k_transpose_w(
    const float* __restrict__ w0, const float* __restrict__ w1,
    const float* __restrict__ w2, const float* __restrict__ w3,
    bf16* __restrict__ o0, bf16* __restrict__ o1,
    bf16* __restrict__ o2, bf16* __restrict__ o3) {
    __shared__ float t[32][33];
    const float* w = blockIdx.z==0 ? w0 : blockIdx.z==1 ? w1 : blockIdx.z==2 ? w2 : w3;
    bf16*       o  = blockIdx.z==0 ? o0 : blockIdx.z==1 ? o1 : blockIdx.z==2 ? o2 : o3;
    int k0 = blockIdx.y*32, n0 = blockIdx.x*32;
    int tx = threadIdx.x & 31, ty = threadIdx.x >> 5;   // 32 x 8
    #pragma unroll
    for (int i = 0; i < 32; i += 8)
        t[ty+i][tx] = w[(size_t)(k0+ty+i)*C_DIM + n0 + tx];
    __syncthreads();
    #pragma unroll
    for (int i = 0; i < 32; i += 8)
        o[(size_t)(n0+ty+i)*C_DIM + k0 + tx] = (bf16)t[tx][ty+i];
}

// ------------- QKV GEMM: [4096x1280] @ [1280x1280] -> Q/K [B,H,S,D], V^T [B,H,D,S] -------------
#define BM 128
#define BN 128
#define BK 32
__global__ __launch_bounds__(256) void k_gemm_qkv(
    const bf16* __restrict__ A,                      // hs_bf [4096][1280]
    const bf16* __restrict__ WqT, const bf16* __restrict__ WkT, const bf16* __restrict__ WvT,
    bf16* __restrict__ Qo, bf16* __restrict__ Ko, bf16* __restrict__ VTo) {
    __shared__ bf16 Al[BM][BK];
    __shared__ bf16 Bl[BN][BK];
    const int z = blockIdx.z;
    const bf16* BT = z==0 ? WqT : z==1 ? WkT : WvT;
    // Q scale folds 1/sqrt(D) AND log2(e) so attn can use raw v_exp (exp2)
    const float scale = (z==0) ? 0.18033688011112042f : 1.0f;
    const int m0 = blockIdx.y * BM, n0 = blockIdx.x * BN;
    const int tid = threadIdx.x, lane = tid & 63, wid = tid >> 6;
    const int wm = wid >> 1, wn = wid & 1;
    const int g = lane >> 4, lr = lane & 15;
    f32x4 acc[4][4];
    #pragma unroll
    for (int i=0;i<4;i++)
        #pragma unroll
        for (int j=0;j<4;j++)
            acc[i][j] = zero4();
    const int srow = tid >> 2, scol = (tid & 3) * 8;
    for (int k0 = 0; k0 < C_DIM; k0 += BK) {
        async_copy16(&Al[srow][scol],    &A [(size_t)(m0+srow)*C_DIM    + k0 + scol]);
        async_copy16(&Al[srow+64][scol], &A [(size_t)(m0+srow+64)*C_DIM + k0 + scol]);
        async_copy16(&Bl[srow][scol],    &BT[(size_t)(n0+srow)*C_DIM    + k0 + scol]);
        async_copy16(&Bl[srow+64][scol], &BT[(size_t)(n0+srow+64)*C_DIM + k0 + scol]);
        __syncthreads();
        bf16x8 af[4], bfr[4];
        #pragma unroll
        for (int mf=0;mf<4;mf++) af[mf]  = *(const bf16x8*)&Al[wm*64+mf*16+lr][g*8];
        #pragma unroll
        for (int nf=0;nf<4;nf++) bfr[nf] = *(const bf16x8*)&Bl[wn*64+nf*16+lr][g*8];
        #pragma unroll
        for (int mf=0;mf<4;mf++)
            #pragma unroll
            for (int nf=0;nf<4;nf++)
                acc[mf][nf] = __builtin_amdgcn_mfma_f32_16x16x32_bf16(af[mf], bfr[nf], acc[mf][nf], 0,0,0);
        __syncthreads();
    }
    if (z == 2) {
        // V: write directly transposed [B,H,D,S]; r-consecutive = s-consecutive
        #pragma unroll
        for (int mf=0;mf<4;mf++) {
            #pragma unroll
            for (int nf=0;nf<4;nf++) {
                int n = n0 + wn*64 + nf*16 + lr;
                int h = n >> 6, d = n & 63;
                int m = m0 + wm*64 + mf*16 + g*4;
                int b = m >> 11, s = m & (S_LEN-1);
                bf16x4 ov;
                #pragma unroll
                for (int r=0;r<4;r++) ov[r] = (bf16)acc[mf][nf][r];
                *(bf16x4*)&VTo[((size_t)(b*H_NUM + h)*D_HEAD + d)*S_LEN + s] = ov;
            }
        }
    } else {
        bf16* Out = (z==0) ? Qo : Ko;
        #pragma unroll
        for (int mf=0;mf<4;mf++) {
            #pragma unroll
            for (int nf=0;nf<4;nf++) {
                int n = n0 + wn*64 + nf*16 + lr;
                int h = n >> 6, d = n & 63;
                #pragma unroll
                for (int r=0;r<4;r++) {
                    int m = m0 + wm*64 + mf*16 + g*4 + r;
                    int b = m >> 11, s = m & (S_LEN-1);
                    Out[(size_t)((b*H_NUM + h)*S_LEN + s)*D_HEAD + d] = (bf16)(acc[mf][nf][r] * scale);
                }
            }
        }
    }
}

// ------------- output GEMM with bias+residual epilogue, fp32 out -------------
__global__ __launch_bounds__(256) void k_gemm_out(
    const bf16* __restrict__ A,                     // Oattn [4096][1280]
    const bf16* __restrict__ WoT,
    const float* __restrict__ bo,
    const float* __restrict__ res,                  // hidden_states fp32
    float* __restrict__ out) {
    __shared__ bf16 Al[BM][BK];
    __shared__ bf16 Bl[BN][BK];
    const int m0 = blockIdx.y * BM, n0 = blockIdx.x * BN;
    const int tid = threadIdx.x, lane = tid & 63, wid = tid >> 6;
    const int wm = wid >> 1, wn = wid & 1;
    const int g = lane >> 4, lr = lane & 15;
    f32x4 acc[4][4];
    #pragma unroll
    for (int i=0;i<4;i++)
        #pragma unroll
        for (int j=0;j<4;j++)
            acc[i][j] = zero4();
    const int srow = tid >> 2, scol = (tid & 3) * 8;
    for (int k0 = 0; k0 < C_DIM; k0 += BK) {
        async_copy16(&Al[srow][scol],    &A  [(size_t)(m0+srow)*C_DIM    + k0 + scol]);
        async_copy16(&Al[srow+64][scol], &A  [(size_t)(m0+srow+64)*C_DIM + k0 + scol]);
        async_copy16(&Bl[srow][scol],    &WoT[(size_t)(n0+srow)*C_DIM    + k0 + scol]);
        async_copy16(&Bl[srow+64][scol], &WoT[(size_t)(n0+srow+64)*C_DIM + k0 + scol]);
        __syncthreads();
        bf16x8 af[4], bfr[4];
        #pragma unroll
        for (int mf=0;mf<4;mf++) af[mf]  = *(const bf16x8*)&Al[wm*64+mf*16+lr][g*8];
        #pragma unroll
        for (int nf=0;nf<4;nf++) bfr[nf] = *(const bf16x8*)&Bl[wn*64+nf*16+lr][g*8];
        #pragma unroll
        for (int mf=0;mf<4;mf++)
            #pragma unroll
            for (int nf=0;nf<4;nf++)
                acc[mf][nf] = __builtin_amdgcn_mfma_f32_16x16x32_bf16(af[mf], bfr[nf], acc[mf][nf], 0,0,0);
        __syncthreads();
    }
    #pragma unroll
    for (int mf=0;mf<4;mf++) {
        #pragma unroll
        for (int nf=0;nf<4;nf++) {
            int n = n0 + wn*64 + nf*16 + lr;
            float bias = bo[n];
            #pragma unroll
            for (int r=0;r<4;r++) {
                int m = m0 + wm*64 + mf*16 + g*4 + r;
                size_t idx = (size_t)m*C_DIM + n;
                out[idx] = acc[mf][nf][r] + bias + res[idx];
            }
        }
    }
}

// ------------- flash attention + loss partials -------------
// Swapped-operand flash attn. Q pre-scaled by log2e/8 -> raw v_exp_f32.
// l via ones-MFMA; s2 via mfma(pb,pb) diagonal (P^T P) -- pb's fragment
// index map is identical as A and B operand, so the same registers serve
// both. XCD swizzle: 1280 blocks = 8 XCDs x 160; 5 whole heads per XCD
// chunk -> K/V L2-resident in one XCD (was 87 MB HBM fetch/dispatch).
#define KVB 64
__global__ __launch_bounds__(256) void k_attn(
    const bf16* __restrict__ Q,    // [B,H,S,D], pre-scaled by log2e/8
    const bf16* __restrict__ Kg,   // [B,H,S,D]
    const bf16* __restrict__ VT,   // [B,H,D,S]
    bf16* __restrict__ O,          // [B,S,H,D]
    float* __restrict__ lossPart) {
    __shared__ bf16 Kl[2][KVB][64];
    __shared__ bf16 Vl[2][D_HEAD][64];   // total LDS = 32768 B exactly

    const int id  = blockIdx.x;              // 0..1279
    const int fid = (id & 7) * 160 + (id >> 3);  // XCD-contiguous (1280%8==0)
    const int bh = fid >> 5;                 // 0..39 (5 whole heads per XCD)
    const int qb = fid & 31;                 // 0..31
    const int b = bh / H_NUM, hh = bh % H_NUM;
    const int tid = threadIdx.x, lane = tid & 63, wid = tid >> 6;
    const int g = lane >> 4, lr = lane & 15;

    const bf16* Kbase = Kg + (size_t)bh * S_LEN * D_HEAD;
    const bf16* Vbase = VT + (size_t)bh * D_HEAD * S_LEN;

    // per-lane q row
    const int qrow = qb*64 + wid*16 + lr;
    const bf16* qp = Q + ((size_t)bh*S_LEN + qrow)*D_HEAD;
    const bf16x8 aq0 = *(const bf16x8*)(qp + g*8);        // Q^T B-frag, d-half 0
    const bf16x8 aq1 = *(const bf16x8*)(qp + 32 + g*8);   // d-half 1

    // ones A-fragment for the l-MFMA
    bf16x8 ones;
    #pragma unroll
    for (int i=0;i<8;i++) ones[i] = (bf16)1.0f;

    // K LDS read-row components (phys kv -> LDS row sigma: swap bits 2,3)
    const int lb7 = (lr & 3) | (((lr >> 2) & 1) << 2);    // LDS row bits 0..2
    const int lhi = ((lr >> 2) & 2) << 3;                 // LDS row bit 4

    f32x4 o_acc[4];
    #pragma unroll
    for (int i=0;i<4;i++) o_acc[i] = zero4();
    f32x4 l_acc = zero4();
    f32x4 s2m   = zero4();

#define STAGE(buf, kv0)                                                          \
    {                                                                            \
        _Pragma("unroll")                                                        \
        for (int pp=0; pp<2; ++pp) {                                             \
            int p = pp*256 + tid;                                                \
            int lrow = p >> 3, gp = p & 7;                                       \
            int tl = (lrow & 51) | ((lrow & 4) << 1) | ((lrow & 8) >> 1);        \
            async_copy16((char*)&Kl[buf][0][0] + p*16,                           \
                         Kbase + (size_t)((kv0) + tl)*D_HEAD                     \
                               + ((gp ^ (lrow & 7)) << 3));                      \
        }                                                                        \
        _Pragma("unroll")                                                        \
        for (int pp=0; pp<2; ++pp) {                                             \
            int p = pp*256 + tid;                                                \
            int drow = p >> 3, gp = p & 7;                                       \
            async_copy16((char*)&Vl[buf][0][0] + p*16,                           \
                         Vbase + (size_t)drow*S_LEN + (kv0)                      \
                               + ((gp ^ (drow & 7)) << 3));                      \
        }                                                                        \
    }

    STAGE(0, 0);
    __syncthreads();

    for (int t = 0; t < S_LEN/KVB; ++t) {
        const int cur = t & 1;
        if (t + 1 < S_LEN/KVB) STAGE(cur^1, (t+1)*KVB);
        const bf16* KB = &Kl[cur][0][0];
        const bf16* VB = &Vl[cur][0][0];

        // QK^T (swapped): acc_p[pair][u][r] = S^T[kv = pair*32+g*8+u*4+r][q=qrow]
        f32x4 accp[2][2];
        #pragma unroll
        for (int pair=0; pair<2; ++pair)
            #pragma unroll
            for (int u=0; u<2; ++u) {
                const bf16* kr = KB + (pair*32 + (u<<3) + lhi + lb7)*64;
                bf16x8 k0 = *(const bf16x8*)(kr + ((g       ^ lb7) << 3));
                bf16x8 k1 = *(const bf16x8*)(kr + (((4 + g) ^ lb7) << 3));
                f32x4 c = zero4();
                c = __builtin_amdgcn_mfma_f32_16x16x32_bf16(k0, aq0, c, 0,0,0);
                c = __builtin_amdgcn_mfma_f32_16x16x32_bf16(k1, aq1, c, 0,0,0);
                accp[pair][u] = c;
            }
        // unnormalized p = 2^(s'): single v_exp_f32 each, lane-local
        bf16x8 pb[2];
        #pragma unroll
        for (int pair=0; pair<2; ++pair)
            #pragma unroll
            for (int u=0; u<2; ++u)
                #pragma unroll
                for (int r=0; r<4; ++r) {
                    float e = __builtin_amdgcn_exp2f(accp[pair][u][r]);
                    pb[pair][u*4+r] = (bf16)e;
                }
        // l via MFMA (A=ones): fully k-reduced Sum(p) per q column
        l_acc = __builtin_amdgcn_mfma_f32_16x16x32_bf16(ones, pb[0], l_acc, 0,0,0);
        l_acc = __builtin_amdgcn_mfma_f32_16x16x32_bf16(ones, pb[1], l_acc, 0,0,0);
        // s2 via MFMA: (P^T P); diagonal = Sum(p^2) per q
        s2m = __builtin_amdgcn_mfma_f32_16x16x32_bf16(pb[0], pb[0], s2m, 0,0,0);
        s2m = __builtin_amdgcn_mfma_f32_16x16x32_bf16(pb[1], pb[1], s2m, 0,0,0);
        // PV: O^T += V^T . P^T
        #pragma unroll
        for (int ds_=0; ds_<4; ++ds_) {
            const bf16* vr = VB + (ds_*16 + lr)*64;
            #pragma unroll
            for (int pair=0; pair<2; ++pair) {
                bf16x8 v = *(const bf16x8*)(vr + (((pair*4 + g) ^ (lr & 7)) << 3));
                o_acc[ds_] = __builtin_amdgcn_mfma_f32_16x16x32_bf16(v, pb[pair], o_acc[ds_], 0,0,0);
            }
        }
        __syncthreads();   // stage t+1 complete; all waves done with cur
    }

    // l is complete per q column (MFMA sums all k)
    const float lfull = l_acc[0];

    // O write: lane owns q=qrow, holds O^T[d = ds_*16+g*4+r]
    const float inv = 1.0f / lfull;
    bf16* orow = O + ((size_t)(b*S_LEN + qrow)*H_NUM + hh)*D_HEAD;
    #pragma unroll
    for (int ds_=0; ds_<4; ++ds_) {
        bf16x4 ov;
        #pragma unroll
        for (int r=0; r<4; ++r) ov[r] = (bf16)(o_acc[ds_][r] * inv);
        *(bf16x4*)(orow + ds_*16 + g*4) = ov;
    }
    // loss partial: diag of s2m holds Sum(p^2) for q=lr on the lane with
    // g == lr>>2 (row==col), element lr&3. One lane per q -> no /4.
    float v = 0.f;
    if (g == (lr >> 2)) v = s2m[lr & 3] / (lfull * lfull);
    #pragma unroll
    for (int msk=1; msk<64; msk<<=1) v += __shfl_xor(v, msk);
    if (lane == 0) lossPart[(bh*32 + qb)*4 + wid] = v;
}

// ------------- deterministic loss reduce -------------
__global__ __launch_bounds__(256) void k_loss(const float* __restrict__ part,
                                              float* __restrict__ out, int n) {
    __shared__ float w[4];
    float s = 0.f;
    for (int i = threadIdx.x; i < n; i += 256) s += part[i];
    #pragma unroll
    for (int msk=1; msk<64; msk<<=1) s += __shfl_xor(s, msk);
    int lane = threadIdx.x & 63, wid = threadIdx.x >> 6;
    if (lane==0) w[wid] = s;
    __syncthreads();
    if (threadIdx.x==0) out[(size_t)M_TOT*C_DIM] = sqrtf(w[0]+w[1]+w[2]+w[3]);
}

extern "C" void kernel_launch(void* const* d_in, const int* in_sizes, int n_in,
                              void* d_out, int out_size, void* d_ws, size_t ws_size,
                              hipStream_t stream) {
    (void)in_sizes; (void)n_in; (void)out_size; (void)ws_size;
    const float* hs = (const float*)d_in[0];
    const float* Wq = (const float*)d_in[1];
    const float* Wk = (const float*)d_in[2];
    const float* Wv = (const float*)d_in[3];
    const float* Wo = (const float*)d_in[4];
    const float* bo = (const float*)d_in[5];
    float* out = (float*)d_out;

    constexpr size_t HS_E = (size_t)M_TOT * C_DIM;       // 5,242,880
    constexpr size_t W_E  = (size_t)C_DIM * C_DIM;       // 1,638,400
    char* ws = (char*)d_ws;
    size_t off = 0;
    bf16* hs_bf = (bf16*)(ws + off); off += HS_E * 2;
    bf16* WqT   = (bf16*)(ws + off); off += W_E * 2;
    bf16* WkT   = (bf16*)(ws + off); off += W_E * 2;
    bf16* WvT   = (bf16*)(ws + off); off += W_E * 2;
    bf16* WoT   = (bf16*)(ws + off); off += W_E * 2;
    bf16* Qb    = (bf16*)(ws + off); off += HS_E * 2;
    bf16* Kb    = (bf16*)(ws + off); off += HS_E * 2;
    bf16* Vtb   = (bf16*)(ws + off); off += HS_E * 2;    // V^T [B,H,D,S], written by gemm
    bf16* Ob    = (bf16*)(ws + off); off += HS_E * 2;
    float* lossPart = (float*)(ws + off); off += 5120 * 4;

    k_convert_hs<<<HS_E/(256*4), 256, 0, stream>>>(hs, hs_bf);
    k_transpose_w<<<dim3(C_DIM/32, C_DIM/32, 4), 256, 0, stream>>>(Wq, Wk, Wv, Wo, WqT, WkT, WvT, WoT);
    k_gemm_qkv<<<dim3(C_DIM/BN, M_TOT/BM, 3), 256, 0, stream>>>(hs_bf, WqT, WkT, WvT, Qb, Kb, Vtb);
    k_attn<<<1280, 256, 0, stream>>>(Qb, Kb, Vtb, Ob, lossPart);
    k_gemm_out<<<dim3(C_DIM/BN, M_TOT/BM), 256, 0, stream>>>(Ob, WoT, bo, hs, out);
    k_loss<<<1, 256, 0, stream>>>(lossPart, out, 5120);
}

// Round 13
// 187.600 us; speedup vs baseline: 1.1643x; 1.0882x over previous
//
#include <hip/hip_runtime.h>
#include <hip/hip_bf16.h>
#include <math.h>

#define B_SZ   2
#define S_LEN  2048
#define C_DIM  1280
#define H_NUM  20
#define D_HEAD 64
#define M_TOT  (B_SZ * S_LEN)          // 4096

typedef __bf16 bf16;
typedef __bf16 bf16x8 __attribute__((ext_vector_type(8)));
typedef __bf16 bf16x4 __attribute__((ext_vector_type(4)));
typedef float  f32x4  __attribute__((ext_vector_type(4)));

__device__ inline f32x4 zero4() { f32x4 z; z[0]=z[1]=z[2]=z[3]=0.f; return z; }

// async global->LDS, 16B per lane. LDS dest must be wave-uniform base + lane*16.
__device__ __forceinline__ void async_copy16(void* lds, const void* g) {
    __builtin_amdgcn_global_load_lds(
        (const __attribute__((address_space(1))) unsigned int*)g,
        (__attribute__((address_space(3))) unsigned int*)lds,
        16, 0, 0);
}

// ---------------- hs fp32 -> bf16 ----------------
__global__ __launch_bounds__(256) void k_convert_hs(const float* __restrict__ in,
                                                    bf16* __restrict__ out) {
    int i = (blockIdx.x * 256 + threadIdx.x) * 4;
    float4 v = *(const float4*)(in + i);
    bf16x4 o; o[0]=(bf16)v.x; o[1]=(bf16)v.y; o[2]=(bf16)v.z; o[3]=(bf16)v.w;
    *(bf16x4*)(out + i) = o;
}

// ------------- W fp32 [K][N] -> bf16 WT [N][K] -------------
__global__ __launch_bounds__(256) void k_transpose_w(
    const float* __restrict__ w0, const float* __restrict__ w1,
    const float* __restrict__ w2, const float* __restrict__ w3,
    bf16* __restrict__ o0, bf16* __restrict__ o1,
    bf16* __restrict__ o2, bf16* __restrict__ o3) {
    __shared__ float t[32][33];
    const float* w = blockIdx.z==0 ? w0 : blockIdx.z==1 ? w1 : blockIdx.z==2 ? w2 : w3;
    bf16*       o  = blockIdx.z==0 ? o0 : blockIdx.z==1 ? o1 : blockIdx.z==2 ? o2 : o3;
    int k0 = blockIdx.y*32, n0 = blockIdx.x*32;
    int tx = threadIdx.x & 31, ty = threadIdx.x >> 5;   // 32 x 8
    #pragma unroll
    for (int i = 0; i < 32; i += 8)
        t[ty+i][tx] = w[(size_t)(k0+ty+i)*C_DIM + n0 + tx];
    __syncthreads();
    #pragma unroll
    for (int i = 0; i < 32; i += 8)
        o[(size_t)(n0+ty+i)*C_DIM + k0 + tx] = (bf16)t[tx][ty+i];
}

// ------------- GEMM core: BK=64, XOR-granule-swizzled LDS -------------
// LDS row = 128 B = 8 granules of 16 B. Staging puts logical granule
// gp^(row&7) at physical slot gp (pre-swizzled global source, linear LDS
// dest for global_load_lds). Reads XOR the same mask -> 2-way conflicts
// (free, m136) instead of 8/16-way.
#define BM 128
#define BN 128
#define BK 64

#define GEMM_STAGE(Al, Bl, Aptr, Bptr, m0, n0, k0)                                \
    {                                                                             \
        _Pragma("unroll")                                                         \
        for (int c = 0; c < 4; ++c) {                                             \
            int p = c*256 + tid;                                                  \
            int row = p >> 3, gp = p & 7, gc = gp ^ (row & 7);                    \
            async_copy16((char*)Al + p*16,                                        \
                         &Aptr[(size_t)((m0)+row)*C_DIM + (k0) + gc*8]);          \
            async_copy16((char*)Bl + p*16,                                        \
                         &Bptr[(size_t)((n0)+row)*C_DIM + (k0) + gc*8]);          \
        }                                                                         \
    }

#define GEMM_COMPUTE(Al, Bl)                                                      \
    {                                                                             \
        _Pragma("unroll")                                                         \
        for (int kk = 0; kk < 2; ++kk) {                                          \
            bf16x8 af[4], bfr[4];                                                 \
            _Pragma("unroll")                                                     \
            for (int mf = 0; mf < 4; ++mf) {                                      \
                int arow = wm*64 + mf*16 + lr;                                    \
                af[mf] = *(const bf16x8*)((char*)Al + arow*128 +                  \
                          (((kk*4 + g) ^ (arow & 7)) << 4));                      \
            }                                                                     \
            _Pragma("unroll")                                                     \
            for (int nf = 0; nf < 4; ++nf) {                                      \
                int brow = wn*64 + nf*16 + lr;                                    \
                bfr[nf] = *(const bf16x8*)((char*)Bl + brow*128 +                 \
                          (((kk*4 + g) ^ (brow & 7)) << 4));                      \
            }                                                                     \
            _Pragma("unroll")                                                     \
            for (int mf = 0; mf < 4; ++mf)                                        \
                _Pragma("unroll")                                                 \
                for (int nf = 0; nf < 4; ++nf)                                    \
                    acc[mf][nf] = __builtin_amdgcn_mfma_f32_16x16x32_bf16(        \
                        af[mf], bfr[nf], acc[mf][nf], 0,0,0);                     \
        }                                                                         \
    }

// ------------- QKV GEMM -> Q/K [B,H,S,D], V^T [B,H,D,S] -------------
__global__ __launch_bounds__(256) void k_gemm_qkv(
    const bf16* __restrict__ A,                      // hs_bf [4096][1280]
    const bf16* __restrict__ WqT, const bf16* __restrict__ WkT, const bf16* __restrict__ WvT,
    bf16* __restrict__ Qo, bf16* __restrict__ Ko, bf16* __restrict__ VTo) {
    __shared__ bf16 Al[BM][BK];
    __shared__ bf16 Bl[BN][BK];
    const int z = blockIdx.z;
    const bf16* BT = z==0 ? WqT : z==1 ? WkT : WvT;
    // Q scale folds 1/sqrt(D) AND log2(e) so attn can use raw v_exp (exp2)
    const float scale = (z==0) ? 0.18033688011112042f : 1.0f;
    const int m0 = blockIdx.y * BM, n0 = blockIdx.x * BN;
    const int tid = threadIdx.x, lane = tid & 63, wid = tid >> 6;
    const int wm = wid >> 1, wn = wid & 1;
    const int g = lane >> 4, lr = lane & 15;
    f32x4 acc[4][4];
    #pragma unroll
    for (int i=0;i<4;i++)
        #pragma unroll
        for (int j=0;j<4;j++)
            acc[i][j] = zero4();
    for (int k0 = 0; k0 < C_DIM; k0 += BK) {
        GEMM_STAGE(Al, Bl, A, BT, m0, n0, k0);
        __syncthreads();
        GEMM_COMPUTE(Al, Bl);
        __syncthreads();
    }
    if (z == 2) {
        // V: write directly transposed [B,H,D,S]; r-consecutive = s-consecutive
        #pragma unroll
        for (int mf=0;mf<4;mf++) {
            #pragma unroll
            for (int nf=0;nf<4;nf++) {
                int n = n0 + wn*64 + nf*16 + lr;
                int h = n >> 6, d = n & 63;
                int m = m0 + wm*64 + mf*16 + g*4;
                int b = m >> 11, s = m & (S_LEN-1);
                bf16x4 ov;
                #pragma unroll
                for (int r=0;r<4;r++) ov[r] = (bf16)acc[mf][nf][r];
                *(bf16x4*)&VTo[((size_t)(b*H_NUM + h)*D_HEAD + d)*S_LEN + s] = ov;
            }
        }
    } else {
        bf16* Out = (z==0) ? Qo : Ko;
        #pragma unroll
        for (int mf=0;mf<4;mf++) {
            #pragma unroll
            for (int nf=0;nf<4;nf++) {
                int n = n0 + wn*64 + nf*16 + lr;
                int h = n >> 6, d = n & 63;
                #pragma unroll
                for (int r=0;r<4;r++) {
                    int m = m0 + wm*64 + mf*16 + g*4 + r;
                    int b = m >> 11, s = m & (S_LEN-1);
                    Out[(size_t)((b*H_NUM + h)*S_LEN + s)*D_HEAD + d] = (bf16)(acc[mf][nf][r] * scale);
                }
            }
        }
    }
}

// ------------- output GEMM with bias+residual epilogue, fp32 out -------------
__global__ __launch_bounds__(256) void k_gemm_out(
    const bf16* __restrict__ A,                     // Oattn [4096][1280]
    const bf16* __restrict__ WoT,
    const float* __restrict__ bo,
    const float* __restrict__ res,                  // hidden_states fp32
    float* __restrict__ out) {
    __shared__ bf16 Al[BM][BK];
    __shared__ bf16 Bl[BN][BK];
    const int m0 = blockIdx.y * BM, n0 = blockIdx.x * BN;
    const int tid = threadIdx.x, lane = tid & 63, wid = tid >> 6;
    const int wm = wid >> 1, wn = wid & 1;
    const int g = lane >> 4, lr = lane & 15;
    f32x4 acc[4][4];
    #pragma unroll
    for (int i=0;i<4;i++)
        #pragma unroll
        for (int j=0;j<4;j++)
            acc[i][j] = zero4();
    for (int k0 = 0; k0 < C_DIM; k0 += BK) {
        GEMM_STAGE(Al, Bl, A, WoT, m0, n0, k0);
        __syncthreads();
        GEMM_COMPUTE(Al, Bl);
        __syncthreads();
    }
    #pragma unroll
    for (int mf=0;mf<4;mf++) {
        #pragma unroll
        for (int nf=0;nf<4;nf++) {
            int n = n0 + wn*64 + nf*16 + lr;
            float bias = bo[n];
            #pragma unroll
            for (int r=0;r<4;r++) {
                int m = m0 + wm*64 + mf*16 + g*4 + r;
                size_t idx = (size_t)m*C_DIM + n;
                out[idx] = acc[mf][nf][r] + bias + res[idx];
            }
        }
    }
}

// ------------- flash attention + loss partials -------------
// Swapped-operand flash attn. Q pre-scaled by log2e/8 -> raw v_exp_f32.
// l via ones-MFMA; s2 via mfma(pb,pb) diagonal. XCD swizzle: 1280 blocks =
// 8 XCDs x 160 -> 5 whole heads per XCD, K/V L2-resident. setprio(1)
// around MFMA clusters (T5).
#define KVB 64
__global__ __launch_bounds__(256) void k_attn(
    const bf16* __restrict__ Q,    // [B,H,S,D], pre-scaled by log2e/8
    const bf16* __restrict__ Kg,   // [B,H,S,D]
    const bf16* __restrict__ VT,   // [B,H,D,S]
    bf16* __restrict__ O,          // [B,S,H,D]
    float* __restrict__ lossPart) {
    __shared__ bf16 Kl[2][KVB][64];
    __shared__ bf16 Vl[2][D_HEAD][64];   // total LDS = 32768 B exactly

    const int id  = blockIdx.x;              // 0..1279
    const int fid = (id & 7) * 160 + (id >> 3);  // XCD-contiguous (1280%8==0)
    const int bh = fid >> 5;                 // 0..39 (5 whole heads per XCD)
    const int qb = fid & 31;                 // 0..31
    const int b = bh / H_NUM, hh = bh % H_NUM;
    const int tid = threadIdx.x, lane = tid & 63, wid = tid >> 6;
    const int g = lane >> 4, lr = lane & 15;

    const bf16* Kbase = Kg + (size_t)bh * S_LEN * D_HEAD;
    const bf16* Vbase = VT + (size_t)bh * D_HEAD * S_LEN;

    // per-lane q row
    const int qrow = qb*64 + wid*16 + lr;
    const bf16* qp = Q + ((size_t)bh*S_LEN + qrow)*D_HEAD;
    const bf16x8 aq0 = *(const bf16x8*)(qp + g*8);        // Q^T B-frag, d-half 0
    const bf16x8 aq1 = *(const bf16x8*)(qp + 32 + g*8);   // d-half 1

    // ones A-fragment for the l-MFMA
    bf16x8 ones;
    #pragma unroll
    for (int i=0;i<8;i++) ones[i] = (bf16)1.0f;

    // K LDS read-row components (phys kv -> LDS row sigma: swap bits 2,3)
    const int lb7 = (lr & 3) | (((lr >> 2) & 1) << 2);    // LDS row bits 0..2
    const int lhi = ((lr >> 2) & 2) << 3;                 // LDS row bit 4

    f32x4 o_acc[4];
    #pragma unroll
    for (int i=0;i<4;i++) o_acc[i] = zero4();
    f32x4 l_acc = zero4();
    f32x4 s2m   = zero4();

#define STAGE(buf, kv0)                                                          \
    {                                                                            \
        _Pragma("unroll")                                                        \
        for (int pp=0; pp<2; ++pp) {                                             \
            int p = pp*256 + tid;                                                \
            int lrow = p >> 3, gp = p & 7;                                       \
            int tl = (lrow & 51) | ((lrow & 4) << 1) | ((lrow & 8) >> 1);        \
            async_copy16((char*)&Kl[buf][0][0] + p*16,                           \
                         Kbase + (size_t)((kv0) + tl)*D_HEAD                     \
                               + ((gp ^ (lrow & 7)) << 3));                      \
        }                                                                        \
        _Pragma("unroll")                                                        \
        for (int pp=0; pp<2; ++pp) {                                             \
            int p = pp*256 + tid;                                                \
            int drow = p >> 3, gp = p & 7;                                       \
            async_copy16((char*)&Vl[buf][0][0] + p*16,                           \
                         Vbase + (size_t)drow*S_LEN + (kv0)                      \
                               + ((gp ^ (drow & 7)) << 3));                      \
        }                                                                        \
    }

    STAGE(0, 0);
    __syncthreads();

    for (int t = 0; t < S_LEN/KVB; ++t) {
        const int cur = t & 1;
        if (t + 1 < S_LEN/KVB) STAGE(cur^1, (t+1)*KVB);
        const bf16* KB = &Kl[cur][0][0];
        const bf16* VB = &Vl[cur][0][0];

        // QK^T (swapped): acc_p[pair][u][r] = S^T[kv = pair*32+g*8+u*4+r][q=qrow]
        f32x4 accp[2][2];
        __builtin_amdgcn_s_setprio(1);
        #pragma unroll
        for (int pair=0; pair<2; ++pair)
            #pragma unroll
            for (int u=0; u<2; ++u) {
                const bf16* kr = KB + (pair*32 + (u<<3) + lhi + lb7)*64;
                bf16x8 k0 = *(const bf16x8*)(kr + ((g       ^ lb7) << 3));
                bf16x8 k1 = *(const bf16x8*)(kr + (((4 + g) ^ lb7) << 3));
                f32x4 c = zero4();
                c = __builtin_amdgcn_mfma_f32_16x16x32_bf16(k0, aq0, c, 0,0,0);
                c = __builtin_amdgcn_mfma_f32_16x16x32_bf16(k1, aq1, c, 0,0,0);
                accp[pair][u] = c;
            }
        __builtin_amdgcn_s_setprio(0);
        // unnormalized p = 2^(s'): single v_exp_f32 each, lane-local
        bf16x8 pb[2];
        #pragma unroll
        for (int pair=0; pair<2; ++pair)
            #pragma unroll
            for (int u=0; u<2; ++u)
                #pragma unroll
                for (int r=0; r<4; ++r) {
                    float e = __builtin_amdgcn_exp2f(accp[pair][u][r]);
                    pb[pair][u*4+r] = (bf16)e;
                }
        __builtin_amdgcn_s_setprio(1);
        // l via MFMA (A=ones): fully k-reduced Sum(p) per q column
        l_acc = __builtin_amdgcn_mfma_f32_16x16x32_bf16(ones, pb[0], l_acc, 0,0,0);
        l_acc = __builtin_amdgcn_mfma_f32_16x16x32_bf16(ones, pb[1], l_acc, 0,0,0);
        // s2 via MFMA: (P^T P); diagonal = Sum(p^2) per q
        s2m = __builtin_amdgcn_mfma_f32_16x16x32_bf16(pb[0], pb[0], s2m, 0,0,0);
        s2m = __builtin_amdgcn_mfma_f32_16x16x32_bf16(pb[1], pb[1], s2m, 0,0,0);
        // PV: O^T += V^T . P^T
        #pragma unroll
        for (int ds_=0; ds_<4; ++ds_) {
            const bf16* vr = VB + (ds_*16 + lr)*64;
            #pragma unroll
            for (int pair=0; pair<2; ++pair) {
                bf16x8 v = *(const bf16x8*)(vr + (((pair*4 + g) ^ (lr & 7)) << 3));
                o_acc[ds_] = __builtin_amdgcn_mfma_f32_16x16x32_bf16(v, pb[pair], o_acc[ds_], 0,0,0);
            }
        }
        __builtin_amdgcn_s_setprio(0);
        __syncthreads();   // stage t+1 complete; all waves done with cur
    }

    // l is complete per q column (MFMA sums all k)
    const float lfull = l_acc[0];

    // O write: lane owns q=qrow, holds O^T[d = ds_*16+g*4+r]
    const float inv = 1.0f / lfull;
    bf16* orow = O + ((size_t)(b*S_LEN + qrow)*H_NUM + hh)*D_HEAD;
    #pragma unroll
    for (int ds_=0; ds_<4; ++ds_) {
        bf16x4 ov;
        #pragma unroll
        for (int r=0; r<4; ++r) ov[r] = (bf16)(o_acc[ds_][r] * inv);
        *(bf16x4*)(orow + ds_*16 + g*4) = ov;
    }
    // loss partial: diag of s2m holds Sum(p^2) for q=lr on the lane with
    // g == lr>>2 (row==col), element lr&3. One lane per q -> no /4.
    float v = 0.f;
    if (g == (lr >> 2)) v = s2m[lr & 3] / (lfull * lfull);
    #pragma unroll
    for (int msk=1; msk<64; msk<<=1) v += __shfl_xor(v, msk);
    if (lane == 0) lossPart[(bh*32 + qb)*4 + wid] = v;
}

// ------------- deterministic loss reduce -------------
__global__ __launch_bounds__(256) void k_loss(const float* __restrict__ part,
                                              float* __restrict__ out, int n) {
    __shared__ float w[4];
    float s = 0.f;
    for (int i = threadIdx.x; i < n; i += 256) s += part[i];
    #pragma unroll
    for (int msk=1; msk<64; msk<<=1) s += __shfl_xor(s, msk);
    int lane = threadIdx.x & 63, wid = threadIdx.x >> 6;
    if (lane==0) w[wid] = s;
    __syncthreads();
    if (threadIdx.x==0) out[(size_t)M_TOT*C_DIM] = sqrtf(w[0]+w[1]+w[2]+w[3]);
}

extern "C" void kernel_launch(void* const* d_in, const int* in_sizes, int n_in,
                              void* d_out, int out_size, void* d_ws, size_t ws_size,
                              hipStream_t stream) {
    (void)in_sizes; (void)n_in; (void)out_size; (void)ws_size;
    const float* hs = (const float*)d_in[0];
    const float* Wq = (const float*)d_in[1];
    const float* Wk = (const float*)d_in[2];
    const float* Wv = (const float*)d_in[3];
    const float* Wo = (const float*)d_in[4];
    const float* bo = (const float*)d_in[5];
    float* out = (float*)d_out;

    constexpr size_t HS_E = (size_t)M_TOT * C_DIM;       // 5,242,880
    constexpr size_t W_E  = (size_t)C_DIM * C_DIM;       // 1,638,400
    char* ws = (char*)d_ws;
    size_t off = 0;
    bf16* hs_bf = (bf16*)(ws + off); off += HS_E * 2;
    bf16* WqT   = (bf16*)(ws + off); off += W_E * 2;
    bf16* WkT   = (bf16*)(ws + off); off += W_E * 2;
    bf16* WvT   = (bf16*)(ws + off); off += W_E * 2;
    bf16* WoT   = (bf16*)(ws + off); off += W_E * 2;
    bf16* Qb    = (bf16*)(ws + off); off += HS_E * 2;
    bf16* Kb    = (bf16*)(ws + off); off += HS_E * 2;
    bf16* Vtb   = (bf16*)(ws + off); off += HS_E * 2;    // V^T [B,H,D,S], written by gemm
    bf16* Ob    = (bf16*)(ws + off); off += HS_E * 2;
    float* lossPart = (float*)(ws + off); off += 5120 * 4;

    k_convert_hs<<<HS_E/(256*4), 256, 0, stream>>>(hs, hs_bf);
    k_transpose_w<<<dim3(C_DIM/32, C_DIM/32, 4), 256, 0, stream>>>(Wq, Wk, Wv, Wo, WqT, WkT, WvT, WoT);
    k_gemm_qkv<<<dim3(C_DIM/BN, M_TOT/BM, 3), 256, 0, stream>>>(hs_bf, WqT, WkT, WvT, Qb, Kb, Vtb);
    k_attn<<<1280, 256, 0, stream>>>(Qb, Kb, Vtb, Ob, lossPart);
    k_gemm_out<<<dim3(C_DIM/BN, M_TOT/BM), 256, 0, stream>>>(Ob, WoT, bo, hs, out);
    k_loss<<<1, 256, 0, stream>>>(lossPart, out, 5120);
}

// Round 14
// 175.332 us; speedup vs baseline: 1.2458x; 1.0700x over previous
//
#include <hip/hip_runtime.h>
#include <hip/hip_bf16.h>
#include <math.h>

#define B_SZ   2
#define S_LEN  2048
#define C_DIM  1280
#define H_NUM  20
#define D_HEAD 64
#define M_TOT  (B_SZ * S_LEN)          // 4096

typedef __bf16 bf16;
typedef __bf16 bf16x8 __attribute__((ext_vector_type(8)));
typedef __bf16 bf16x4 __attribute__((ext_vector_type(4)));
typedef float  f32x4  __attribute__((ext_vector_type(4)));

__device__ inline f32x4 zero4() { f32x4 z; z[0]=z[1]=z[2]=z[3]=0.f; return z; }

// async global->LDS, 16B per lane. LDS dest must be wave-uniform base + lane*16.
__device__ __forceinline__ void async_copy16(void* lds, const void* g) {
    __builtin_amdgcn_global_load_lds(
        (const __attribute__((address_space(1))) unsigned int*)g,
        (__attribute__((address_space(3))) unsigned int*)lds,
        16, 0, 0);
}

// ---------------- hs fp32 -> bf16 ----------------
__global__ __launch_bounds__(256) void k_convert_hs(const float* __restrict__ in,
                                                    bf16* __restrict__ out) {
    int i = (blockIdx.x * 256 + threadIdx.x) * 4;
    float4 v = *(const float4*)(in + i);
    bf16x4 o; o[0]=(bf16)v.x; o[1]=(bf16)v.y; o[2]=(bf16)v.z; o[3]=(bf16)v.w;
    *(bf16x4*)(out + i) = o;
}

// ------------- W fp32 [K][N] -> bf16 WT [N][K] -------------
__global__ __launch_bounds__(256) void k_transpose_w(
    const float* __restrict__ w0, const float* __restrict__ w1,
    const float* __restrict__ w2, const float* __restrict__ w3,
    bf16* __restrict__ o0, bf16* __restrict__ o1,
    bf16* __restrict__ o2, bf16* __restrict__ o3) {
    __shared__ float t[32][33];
    const float* w = blockIdx.z==0 ? w0 : blockIdx.z==1 ? w1 : blockIdx.z==2 ? w2 : w3;
    bf16*       o  = blockIdx.z==0 ? o0 : blockIdx.z==1 ? o1 : blockIdx.z==2 ? o2 : o3;
    int k0 = blockIdx.y*32, n0 = blockIdx.x*32;
    int tx = threadIdx.x & 31, ty = threadIdx.x >> 5;   // 32 x 8
    #pragma unroll
    for (int i = 0; i < 32; i += 8)
        t[ty+i][tx] = w[(size_t)(k0+ty+i)*C_DIM + n0 + tx];
    __syncthreads();
    #pragma unroll
    for (int i = 0; i < 32; i += 8)
        o[(size_t)(n0+ty+i)*C_DIM + k0 + tx] = (bf16)t[tx][ty+i];
}

// ------------- Fused QKV GEMM: 256x256 tile, BK=32, triple-buffered LDS,
// raw s_barrier + counted vmcnt (loads for tile t+2 stay in flight across
// the barrier; __syncthreads would drain vmcnt->0 = the known ~20% stall).
// N = 3840 (WqT|WkT|WvT contiguous); 1280%256==0 so each N-tile is within
// one weight. 8 waves (2M x 4N), per-wave output 128x64, acc[8][4]. -------------
#define QBM 256
#define QBN 256
#define QBK 32
#define QNT (C_DIM / QBK)   // 40
__global__ __launch_bounds__(512, 2) void k_gemm_qkv(
    const bf16* __restrict__ A,      // hs_bf [4096][1280]
    const bf16* __restrict__ Wcat,   // [3840][1280] = WqT|WkT|WvT
    bf16* __restrict__ Qo, bf16* __restrict__ Ko, bf16* __restrict__ VTo) {
    __shared__ bf16 lds[3][2][QBM][QBK];   // 96 KB
    const int m0  = blockIdx.y * QBM;
    const int nx  = blockIdx.x;            // 0..14
    const int z   = nx / 5;                // which weight
    const int nw0 = (nx % 5) * QBN;        // within-weight col base
    const int ng0 = nx * QBN;              // row into Wcat
    const int tid = threadIdx.x, lane = tid & 63, wid = tid >> 6;
    const int wm = wid >> 2, wn = wid & 3;
    const int g = lane >> 4, lr = lane & 15;
    const float scale = (z==0) ? 0.18033688011112042f : 1.0f;  // log2e/8 for Q

    f32x4 acc[8][4];
    #pragma unroll
    for (int i=0;i<8;i++)
        #pragma unroll
        for (int j=0;j<4;j++)
            acc[i][j] = zero4();

#define QSTAGE(bf, kt)                                                       \
    { const int k0_ = (kt)*QBK;                                              \
      _Pragma("unroll")                                                      \
      for (int c = 0; c < 2; ++c) {                                          \
        int p = c*512 + tid;                                                 \
        int row = p >> 2, gp = p & 3;                                        \
        async_copy16((char*)&lds[bf][0][0][0] + p*16,                        \
                     &A[(size_t)(m0+row)*C_DIM + k0_ + gp*8]);               \
        async_copy16((char*)&lds[bf][1][0][0] + p*16,                        \
                     &Wcat[(size_t)(ng0+row)*C_DIM + k0_ + gp*8]);           \
      } }

    QSTAGE(0, 0);
    QSTAGE(1, 1);
    asm volatile("s_waitcnt vmcnt(4)" ::: "memory");   // tile0 landed; tile1 in flight
    __builtin_amdgcn_s_barrier();

    int cur = 0;
    for (int t = 0; t < QNT; ++t) {
        if (t + 2 < QNT) {
            int sb = cur + 2; if (sb >= 3) sb -= 3;
            QSTAGE(sb, t + 2);                          // issue early, fly across barrier
        }
        const bf16* AB = &lds[cur][0][0][0];
        const bf16* BB = &lds[cur][1][0][0];
        bf16x8 af[8], bfr[4];
        #pragma unroll
        for (int mf = 0; mf < 8; ++mf)
            af[mf] = *(const bf16x8*)(AB + (wm*128 + mf*16 + lr)*QBK + g*8);
        #pragma unroll
        for (int nf = 0; nf < 4; ++nf)
            bfr[nf] = *(const bf16x8*)(BB + (wn*64 + nf*16 + lr)*QBK + g*8);
        #pragma unroll
        for (int mf = 0; mf < 8; ++mf)
            #pragma unroll
            for (int nf = 0; nf < 4; ++nf)
                acc[mf][nf] = __builtin_amdgcn_mfma_f32_16x16x32_bf16(
                    af[mf], bfr[nf], acc[mf][nf], 0,0,0);
        // lgkmcnt(0): LDS reads done before other waves overwrite this buffer.
        // vmcnt(4): wait tile t+1's 4 loads (oldest); tile t+2's 4 stay in flight.
        if (t + 2 < QNT) asm volatile("s_waitcnt vmcnt(4) lgkmcnt(0)" ::: "memory");
        else             asm volatile("s_waitcnt vmcnt(0) lgkmcnt(0)" ::: "memory");
        __builtin_amdgcn_s_barrier();
        if (++cur == 3) cur = 0;
    }

    if (z == 2) {
        // V: write directly transposed [B,H,D,S]
        #pragma unroll
        for (int mf=0;mf<8;mf++) {
            #pragma unroll
            for (int nf=0;nf<4;nf++) {
                int n = nw0 + wn*64 + nf*16 + lr;
                int h = n >> 6, d = n & 63;
                int m = m0 + wm*128 + mf*16 + g*4;
                int b = m >> 11, s = m & (S_LEN-1);
                bf16x4 ov;
                #pragma unroll
                for (int r=0;r<4;r++) ov[r] = (bf16)acc[mf][nf][r];
                *(bf16x4*)&VTo[((size_t)(b*H_NUM + h)*D_HEAD + d)*S_LEN + s] = ov;
            }
        }
    } else {
        bf16* Out = (z==0) ? Qo : Ko;
        #pragma unroll
        for (int mf=0;mf<8;mf++) {
            #pragma unroll
            for (int nf=0;nf<4;nf++) {
                int n = nw0 + wn*64 + nf*16 + lr;
                int h = n >> 6, d = n & 63;
                #pragma unroll
                for (int r=0;r<4;r++) {
                    int m = m0 + wm*128 + mf*16 + g*4 + r;
                    int b = m >> 11, s = m & (S_LEN-1);
                    Out[(size_t)((b*H_NUM + h)*S_LEN + s)*D_HEAD + d] = (bf16)(acc[mf][nf][r] * scale);
                }
            }
        }
    }
}

// ------------- output GEMM (128x128, BK=64, swizzled): bias+residual, fp32 out -------------
#define BM 128
#define BN 128
#define BK 64

#define GEMM_STAGE(Al, Bl, Aptr, Bptr, m0, n0, k0)                                \
    {                                                                             \
        _Pragma("unroll")                                                         \
        for (int c = 0; c < 4; ++c) {                                             \
            int p = c*256 + tid;                                                  \
            int row = p >> 3, gp = p & 7, gc = gp ^ (row & 7);                    \
            async_copy16((char*)Al + p*16,                                        \
                         &Aptr[(size_t)((m0)+row)*C_DIM + (k0) + gc*8]);          \
            async_copy16((char*)Bl + p*16,                                        \
                         &Bptr[(size_t)((n0)+row)*C_DIM + (k0) + gc*8]);          \
        }                                                                         \
    }

#define GEMM_COMPUTE(Al, Bl)                                                      \
    {                                                                             \
        _Pragma("unroll")                                                         \
        for (int kk = 0; kk < 2; ++kk) {                                          \
            bf16x8 af[4], bfr[4];                                                 \
            _Pragma("unroll")                                                     \
            for (int mf = 0; mf < 4; ++mf) {                                      \
                int arow = wm*64 + mf*16 + lr;                                    \
                af[mf] = *(const bf16x8*)((char*)Al + arow*128 +                  \
                          (((kk*4 + g) ^ (arow & 7)) << 4));                      \
            }                                                                     \
            _Pragma("unroll")                                                     \
            for (int nf = 0; nf < 4; ++nf) {                                      \
                int brow = wn*64 + nf*16 + lr;                                    \
                bfr[nf] = *(const bf16x8*)((char*)Bl + brow*128 +                 \
                          (((kk*4 + g) ^ (brow & 7)) << 4));                      \
            }                                                                     \
            _Pragma("unroll")                                                     \
            for (int mf = 0; mf < 4; ++mf)                                        \
                _Pragma("unroll")                                                 \
                for (int nf = 0; nf < 4; ++nf)                                    \
                    acc[mf][nf] = __builtin_amdgcn_mfma_f32_16x16x32_bf16(        \
                        af[mf], bfr[nf], acc[mf][nf], 0,0,0);                     \
        }                                                                         \
    }

__global__ __launch_bounds__(256) void k_gemm_out(
    const bf16* __restrict__ A,                     // Oattn [4096][1280]
    const bf16* __restrict__ WoT,
    const float* __restrict__ bo,
    const float* __restrict__ res,                  // hidden_states fp32
    float* __restrict__ out) {
    __shared__ bf16 Al[BM][BK];
    __shared__ bf16 Bl[BN][BK];
    const int m0 = blockIdx.y * BM, n0 = blockIdx.x * BN;
    const int tid = threadIdx.x, lane = tid & 63, wid = tid >> 6;
    const int wm = wid >> 1, wn = wid & 1;
    const int g = lane >> 4, lr = lane & 15;
    f32x4 acc[4][4];
    #pragma unroll
    for (int i=0;i<4;i++)
        #pragma unroll
        for (int j=0;j<4;j++)
            acc[i][j] = zero4();
    for (int k0 = 0; k0 < C_DIM; k0 += BK) {
        GEMM_STAGE(Al, Bl, A, WoT, m0, n0, k0);
        __syncthreads();
        GEMM_COMPUTE(Al, Bl);
        __syncthreads();
    }
    #pragma unroll
    for (int mf=0;mf<4;mf++) {
        #pragma unroll
        for (int nf=0;nf<4;nf++) {
            int n = n0 + wn*64 + nf*16 + lr;
            float bias = bo[n];
            #pragma unroll
            for (int r=0;r<4;r++) {
                int m = m0 + wm*64 + mf*16 + g*4 + r;
                size_t idx = (size_t)m*C_DIM + n;
                out[idx] = acc[mf][nf][r] + bias + res[idx];
            }
        }
    }
}

// ------------- flash attention + loss partials -------------
// Swapped-operand flash attn. Q pre-scaled by log2e/8 -> raw v_exp_f32.
// l via ones-MFMA; s2 via mfma(pb,pb) diagonal. XCD swizzle: 1280 blocks =
// 8 XCDs x 160 -> 5 whole heads per XCD, K/V L2-resident. setprio(1)
// around MFMA clusters (T5).
#define KVB 64
__global__ __launch_bounds__(256) void k_attn(
    const bf16* __restrict__ Q,    // [B,H,S,D], pre-scaled by log2e/8
    const bf16* __restrict__ Kg,   // [B,H,S,D]
    const bf16* __restrict__ VT,   // [B,H,D,S]
    bf16* __restrict__ O,          // [B,S,H,D]
    float* __restrict__ lossPart) {
    __shared__ bf16 Kl[2][KVB][64];
    __shared__ bf16 Vl[2][D_HEAD][64];   // total LDS = 32768 B exactly

    const int id  = blockIdx.x;              // 0..1279
    const int fid = (id & 7) * 160 + (id >> 3);  // XCD-contiguous (1280%8==0)
    const int bh = fid >> 5;                 // 0..39 (5 whole heads per XCD)
    const int qb = fid & 31;                 // 0..31
    const int b = bh / H_NUM, hh = bh % H_NUM;
    const int tid = threadIdx.x, lane = tid & 63, wid = tid >> 6;
    const int g = lane >> 4, lr = lane & 15;

    const bf16* Kbase = Kg + (size_t)bh * S_LEN * D_HEAD;
    const bf16* Vbase = VT + (size_t)bh * D_HEAD * S_LEN;

    // per-lane q row
    const int qrow = qb*64 + wid*16 + lr;
    const bf16* qp = Q + ((size_t)bh*S_LEN + qrow)*D_HEAD;
    const bf16x8 aq0 = *(const bf16x8*)(qp + g*8);        // Q^T B-frag, d-half 0
    const bf16x8 aq1 = *(const bf16x8*)(qp + 32 + g*8);   // d-half 1

    // ones A-fragment for the l-MFMA
    bf16x8 ones;
    #pragma unroll
    for (int i=0;i<8;i++) ones[i] = (bf16)1.0f;

    // K LDS read-row components (phys kv -> LDS row sigma: swap bits 2,3)
    const int lb7 = (lr & 3) | (((lr >> 2) & 1) << 2);    // LDS row bits 0..2
    const int lhi = ((lr >> 2) & 2) << 3;                 // LDS row bit 4

    f32x4 o_acc[4];
    #pragma unroll
    for (int i=0;i<4;i++) o_acc[i] = zero4();
    f32x4 l_acc = zero4();
    f32x4 s2m   = zero4();

#define STAGE(buf, kv0)                                                          \
    {                                                                            \
        _Pragma("unroll")                                                        \
        for (int pp=0; pp<2; ++pp) {                                             \
            int p = pp*256 + tid;                                                \
            int lrow = p >> 3, gp = p & 7;                                       \
            int tl = (lrow & 51) | ((lrow & 4) << 1) | ((lrow & 8) >> 1);        \
            async_copy16((char*)&Kl[buf][0][0] + p*16,                           \
                         Kbase + (size_t)((kv0) + tl)*D_HEAD                     \
                               + ((gp ^ (lrow & 7)) << 3));                      \
        }                                                                        \
        _Pragma("unroll")                                                        \
        for (int pp=0; pp<2; ++pp) {                                             \
            int p = pp*256 + tid;                                                \
            int drow = p >> 3, gp = p & 7;                                       \
            async_copy16((char*)&Vl[buf][0][0] + p*16,                           \
                         Vbase + (size_t)drow*S_LEN + (kv0)                      \
                               + ((gp ^ (drow & 7)) << 3));                      \
        }                                                                        \
    }

    STAGE(0, 0);
    __syncthreads();

    for (int t = 0; t < S_LEN/KVB; ++t) {
        const int cur = t & 1;
        if (t + 1 < S_LEN/KVB) STAGE(cur^1, (t+1)*KVB);
        const bf16* KB = &Kl[cur][0][0];
        const bf16* VB = &Vl[cur][0][0];

        // QK^T (swapped): acc_p[pair][u][r] = S^T[kv = pair*32+g*8+u*4+r][q=qrow]
        f32x4 accp[2][2];
        __builtin_amdgcn_s_setprio(1);
        #pragma unroll
        for (int pair=0; pair<2; ++pair)
            #pragma unroll
            for (int u=0; u<2; ++u) {
                const bf16* kr = KB + (pair*32 + (u<<3) + lhi + lb7)*64;
                bf16x8 k0 = *(const bf16x8*)(kr + ((g       ^ lb7) << 3));
                bf16x8 k1 = *(const bf16x8*)(kr + (((4 + g) ^ lb7) << 3));
                f32x4 c = zero4();
                c = __builtin_amdgcn_mfma_f32_16x16x32_bf16(k0, aq0, c, 0,0,0);
                c = __builtin_amdgcn_mfma_f32_16x16x32_bf16(k1, aq1, c, 0,0,0);
                accp[pair][u] = c;
            }
        __builtin_amdgcn_s_setprio(0);
        // unnormalized p = 2^(s'): single v_exp_f32 each, lane-local
        bf16x8 pb[2];
        #pragma unroll
        for (int pair=0; pair<2; ++pair)
            #pragma unroll
            for (int u=0; u<2; ++u)
                #pragma unroll
                for (int r=0; r<4; ++r) {
                    float e = __builtin_amdgcn_exp2f(accp[pair][u][r]);
                    pb[pair][u*4+r] = (bf16)e;
                }
        __builtin_amdgcn_s_setprio(1);
        // l via MFMA (A=ones): fully k-reduced Sum(p) per q column
        l_acc = __builtin_amdgcn_mfma_f32_16x16x32_bf16(ones, pb[0], l_acc, 0,0,0);
        l_acc = __builtin_amdgcn_mfma_f32_16x16x32_bf16(ones, pb[1], l_acc, 0,0,0);
        // s2 via MFMA: (P^T P); diagonal = Sum(p^2) per q
        s2m = __builtin_amdgcn_mfma_f32_16x16x32_bf16(pb[0], pb[0], s2m, 0,0,0);
        s2m = __builtin_amdgcn_mfma_f32_16x16x32_bf16(pb[1], pb[1], s2m, 0,0,0);
        // PV: O^T += V^T . P^T
        #pragma unroll
        for (int ds_=0; ds_<4; ++ds_) {
            const bf16* vr = VB + (ds_*16 + lr)*64;
            #pragma unroll
            for (int pair=0; pair<2; ++pair) {
                bf16x8 v = *(const bf16x8*)(vr + (((pair*4 + g) ^ (lr & 7)) << 3));
                o_acc[ds_] = __builtin_amdgcn_mfma_f32_16x16x32_bf16(v, pb[pair], o_acc[ds_], 0,0,0);
            }
        }
        __builtin_amdgcn_s_setprio(0);
        __syncthreads();   // stage t+1 complete; all waves done with cur
    }

    // l is complete per q column (MFMA sums all k)
    const float lfull = l_acc[0];

    // O write: lane owns q=qrow, holds O^T[d = ds_*16+g*4+r]
    const float inv = 1.0f / lfull;
    bf16* orow = O + ((size_t)(b*S_LEN + qrow)*H_NUM + hh)*D_HEAD;
    #pragma unroll
    for (int ds_=0; ds_<4; ++ds_) {
        bf16x4 ov;
        #pragma unroll
        for (int r=0; r<4; ++r) ov[r] = (bf16)(o_acc[ds_][r] * inv);
        *(bf16x4*)(orow + ds_*16 + g*4) = ov;
    }
    // loss partial: diag of s2m holds Sum(p^2) for q=lr on the lane with
    // g == lr>>2 (row==col), element lr&3. One lane per q -> no /4.
    float v = 0.f;
    if (g == (lr >> 2)) v = s2m[lr & 3] / (lfull * lfull);
    #pragma unroll
    for (int msk=1; msk<64; msk<<=1) v += __shfl_xor(v, msk);
    if (lane == 0) lossPart[(bh*32 + qb)*4 + wid] = v;
}

// ------------- deterministic loss reduce -------------
__global__ __launch_bounds__(256) void k_loss(const float* __restrict__ part,
                                              float* __restrict__ out, int n) {
    __shared__ float w[4];
    float s = 0.f;
    for (int i = threadIdx.x; i < n; i += 256) s += part[i];
    #pragma unroll
    for (int msk=1; msk<64; msk<<=1) s += __shfl_xor(s, msk);
    int lane = threadIdx.x & 63, wid = threadIdx.x >> 6;
    if (lane==0) w[wid] = s;
    __syncthreads();
    if (threadIdx.x==0) out[(size_t)M_TOT*C_DIM] = sqrtf(w[0]+w[1]+w[2]+w[3]);
}

extern "C" void kernel_launch(void* const* d_in, const int* in_sizes, int n_in,
                              void* d_out, int out_size, void* d_ws, size_t ws_size,
                              hipStream_t stream) {
    (void)in_sizes; (void)n_in; (void)out_size; (void)ws_size;
    const float* hs = (const float*)d_in[0];
    const float* Wq = (const float*)d_in[1];
    const float* Wk = (const float*)d_in[2];
    const float* Wv = (const float*)d_in[3];
    const float* Wo = (const float*)d_in[4];
    const float* bo = (const float*)d_in[5];
    float* out = (float*)d_out;

    constexpr size_t HS_E = (size_t)M_TOT * C_DIM;       // 5,242,880
    constexpr size_t W_E  = (size_t)C_DIM * C_DIM;       // 1,638,400
    char* ws = (char*)d_ws;
    size_t off = 0;
    bf16* hs_bf = (bf16*)(ws + off); off += HS_E * 2;
    bf16* WqT   = (bf16*)(ws + off); off += W_E * 2;     // WqT|WkT|WvT contiguous
    bf16* WkT   = (bf16*)(ws + off); off += W_E * 2;
    bf16* WvT   = (bf16*)(ws + off); off += W_E * 2;
    bf16* WoT   = (bf16*)(ws + off); off += W_E * 2;
    bf16* Qb    = (bf16*)(ws + off); off += HS_E * 2;
    bf16* Kb    = (bf16*)(ws + off); off += HS_E * 2;
    bf16* Vtb   = (bf16*)(ws + off); off += HS_E * 2;    // V^T [B,H,D,S], written by gemm
    bf16* Ob    = (bf16*)(ws + off); off += HS_E * 2;
    float* lossPart = (float*)(ws + off); off += 5120 * 4;

    k_convert_hs<<<HS_E/(256*4), 256, 0, stream>>>(hs, hs_bf);
    k_transpose_w<<<dim3(C_DIM/32, C_DIM/32, 4), 256, 0, stream>>>(Wq, Wk, Wv, Wo, WqT, WkT, WvT, WoT);
    k_gemm_qkv<<<dim3(3*C_DIM/QBN, M_TOT/QBM), 512, 0, stream>>>(hs_bf, WqT, Qb, Kb, Vtb);
    k_attn<<<1280, 256, 0, stream>>>(Qb, Kb, Vtb, Ob, lossPart);
    k_gemm_out<<<dim3(C_DIM/BN, M_TOT/BM), 256, 0, stream>>>(Ob, WoT, bo, hs, out);
    k_loss<<<1, 256, 0, stream>>>(lossPart, out, 5120);
}